// Round 9
// baseline (311.584 us; speedup 1.0000x reference)
//
#include <hip/hip_runtime.h>

typedef __bf16 bf16x8 __attribute__((ext_vector_type(8)));
typedef __bf16 bf16x4 __attribute__((ext_vector_type(4)));
typedef float  f32x4  __attribute__((ext_vector_type(4)));

__device__ __forceinline__ f32x4 mfma_bf16(bf16x8 a, bf16x8 b, f32x4 c) {
  return __builtin_amdgcn_mfma_f32_16x16x32_bf16(a, b, c, 0, 0, 0);
}
// Packed B-fragment load: Bp[((kt*NT+nt)*64+lane)*8 .. +7]
__device__ __forceinline__ bf16x8 ldB(const __bf16* Bp, int kt, int NT, int nt,
                                      int lane) {
  return *reinterpret_cast<const bf16x8*>(Bp + (((size_t)kt * NT + nt) * 64 + lane) * 8);
}

// Grid barrier -- ONLY for small grids (<=~256 blocks, light phases).
// R4 lesson: 512-block barriers with heavy phases cost 100s of us.
__device__ __forceinline__ void gridbar(int* cnt, int target) {
  __syncthreads();
  if (threadIdx.x == 0) {
    __threadfence();
    __hip_atomic_fetch_add(cnt, 1, __ATOMIC_RELEASE, __HIP_MEMORY_SCOPE_AGENT);
    while (__hip_atomic_load(cnt, __ATOMIC_RELAXED, __HIP_MEMORY_SCOPE_AGENT) < target)
      __builtin_amdgcn_s_sleep(4);
    __threadfence();
  }
  __syncthreads();
}

// ---------------------------------------------------------------------------
// All weight packs in ONE kernel + zero G + zero counters.
// ---------------------------------------------------------------------------
__global__ void pack_all(const float* __restrict__ W1, const float* __restrict__ W2,
                         const float* __restrict__ Wg1, const float* __restrict__ Wg2,
                         const float* __restrict__ Wr1, const float* __restrict__ Wr2,
                         __bf16* __restrict__ W1p, __bf16* __restrict__ W2p,
                         __bf16* __restrict__ Wg1p, __bf16* __restrict__ Wg2p,
                         __bf16* __restrict__ Wr1p, __bf16* __restrict__ Wr2p,
                         float* __restrict__ G, int* __restrict__ cnt) {
  int bx = blockIdx.x;
  int lane = threadIdx.x;
  if (bx >= 1104) {  // zero G (256x256 f32): 32 blocks x 64 thr x 8 float4
    if (bx == 1104 && lane < 2) cnt[lane] = 0;  // [0]=masks_ec bar, [1]=pdone
    float4* g = (float4*)G;
    int base = (bx - 1104) * 512 + lane;
#pragma unroll
    for (int i = 0; i < 8; ++i) g[base + i * 64] = make_float4(0.f, 0.f, 0.f, 0.f);
    return;
  }
  const float* W; __bf16* out; int N, K, NT, local;
  if (bx < 544)      { W = W1;  out = W1p;  N = 256; K = 1080; NT = 16; local = bx; }
  else if (bx < 672) { W = W2;  out = W2p;  N = 256; K = 256;  NT = 16; local = bx - 544; }
  else if (bx < 784) { W = Wg1; out = Wg1p; N = 256; K = 200;  NT = 16; local = bx - 672; }
  else if (bx < 848) { W = Wg2; out = Wg2p; N = 128; K = 256;  NT = 8;  local = bx - 784; }
  else if (bx < 912) { W = Wr1; out = Wr1p; N = 256; K = 128;  NT = 16; local = bx - 848; }
  else               { W = Wr2; out = Wr2p; N = 360; K = 256;  NT = 24; local = bx - 912; }
  int nt = local % NT, kt = local / NT;
  int n = nt * 16 + (lane & 15);
  int k0 = kt * 32 + (lane >> 4) * 8;
  bf16x8 v;
#pragma unroll
  for (int e = 0; e < 8; ++e) {
    int k = k0 + e;
    float xv = (n < N && k < K) ? W[(size_t)n * K + k] : 0.f;
    v[e] = (__bf16)xv;
  }
  *reinterpret_cast<bf16x8*>(out + ((size_t)local * 64 + lane) * 8) = v;
}

// ---------------------------------------------------------------------------
// Fused surrogate v3 (proven R8): tile 32x256, 8 waves, grid 512 -> 4 waves/SIMD.
// ---------------------------------------------------------------------------
__global__ __launch_bounds__(512) void h1h2_fused(
    const float* __restrict__ x, const __bf16* __restrict__ W1p,
    const float* __restrict__ b1, const __bf16* __restrict__ W2p,
    const float* __restrict__ b2, __bf16* __restrict__ m1T,
    __bf16* __restrict__ m2T) {
  __shared__ __bf16 Alds[32][68];    // 64-wide K-slab, stride 68 (~2-way banks)
  __shared__ __bf16 h1s[32][264];    // relu(h1)
  int tid = threadIdx.x;
  int lane = tid & 63, wid = tid >> 6;
  int wr = wid >> 2, wc = wid & 3;
  int rowBase = blockIdx.x * 32;
  int sr = tid >> 4, sc = (tid & 15) * 4;   // 32 rows x 16 thr x 4 floats
  const float* aSrc = x + (size_t)(rowBase + sr) * 1080;
  f32x4 acc[4] = {};
  float4 c0, c1;
  auto LD = [&](int s, float4& d) {
    int gk = s * 64 + sc;
    d = (gk < 1080) ? *(const float4*)(aSrc + gk) : make_float4(0.f, 0.f, 0.f, 0.f);
  };
  LD(0, c0);
  LD(1, c1);
  for (int s = 0; s < 17; ++s) {
    bf16x4 w4;
    w4[0] = (__bf16)c0.x; w4[1] = (__bf16)c0.y;
    w4[2] = (__bf16)c0.z; w4[3] = (__bf16)c0.w;
    *reinterpret_cast<bf16x4*>(&Alds[sr][sc]) = w4;
    __syncthreads();
    c0 = c1;
    if (s + 2 < 17) LD(s + 2, c1);
    int arow = wr * 16 + (lane & 15);
#pragma unroll
    for (int ks = 0; ks < 2; ++ks) {
      int ak = ks * 32 + (lane >> 4) * 8;
      bf16x8 a0 = *reinterpret_cast<const bf16x8*>(&Alds[arow][ak]);
      int kt = s * 2 + ks;
#pragma unroll
      for (int n = 0; n < 4; ++n) {
        bf16x8 bv = ldB(W1p, kt, 16, wc * 4 + n, lane);
        acc[n] = mfma_bf16(a0, bv, acc[n]);
      }
    }
    __syncthreads();
  }
  int q4 = (lane >> 4) * 4;
#pragma unroll
  for (int n = 0; n < 4; ++n) {
    int col = wc * 64 + n * 16 + (lane & 15);
    float bb = b1[col];
#pragma unroll
    for (int j = 0; j < 4; ++j) {
      int rl = wr * 16 + q4 + j;
      float h = acc[n][j] + bb;
      m1T[(size_t)col * 16384 + rowBase + rl] = (__bf16)(h > 0.f ? 1.f : 0.f);
      h1s[rl][col] = (__bf16)fmaxf(h, 0.f);
    }
  }
  __syncthreads();
  // ---- h2 phase: K=256 from LDS ----
  f32x4 acc2[4] = {};
#pragma unroll
  for (int ks = 0; ks < 8; ++ks) {
    int arow = wr * 16 + (lane & 15), ak = ks * 32 + (lane >> 4) * 8;
    bf16x8 a0 = *reinterpret_cast<const bf16x8*>(&h1s[arow][ak]);
#pragma unroll
    for (int n = 0; n < 4; ++n) {
      bf16x8 bv = ldB(W2p, ks, 16, wc * 4 + n, lane);
      acc2[n] = mfma_bf16(a0, bv, acc2[n]);
    }
  }
#pragma unroll
  for (int n = 0; n < 4; ++n) {
    int col = wc * 64 + n * 16 + (lane & 15);
    float bb = b2[col];
#pragma unroll
    for (int j = 0; j < 4; ++j) {
      int rl = wr * 16 + q4 + j;
      float h = acc2[n][j] + bb;
      m2T[(size_t)col * 16384 + rowBase + rl] = (__bf16)(h > 0.f ? 1.f : 0.f);
    }
  }
}

// ---------------------------------------------------------------------------
// 64x64-tile f32 GEMM body over K range [kBeg,kEnd) (multiples of 16, <=256).
// Optional A2 elementwise multiply; optional 4-chunk fixed-order B sum.
// ---------------------------------------------------------------------------
__device__ void small_body2(float (*As)[17], float (*Bs)[65], int t,
                            const float* __restrict__ A, const float* __restrict__ A2,
                            int lda, const float* __restrict__ Bm, int ldb,
                            bool sum4, size_t bStride, float* __restrict__ C,
                            int ldc, int M, int N, int kBeg, int kEnd,
                            int m0, int n0) {
  int tx = t & 15, ty = t >> 4;
  float acc[4][4] = {};
  for (int k0 = kBeg; k0 < kEnd; k0 += 16) {
#pragma unroll
    for (int i = 0; i < 4; ++i) {
      int idx = t * 4 + i;
      int r = idx >> 4, kk = idx & 15;
      int gm = m0 + r, gk = k0 + kk;
      float v = (gm < M) ? A[(size_t)gm * lda + gk] : 0.f;
      if (A2 && gm < M) v *= A2[(size_t)gm * lda + gk];
      As[r][kk] = v;
      int kk2 = idx >> 6, cc = idx & 63;
      int gk2 = k0 + kk2, gn = n0 + cc;
      float bv = 0.f;
      if (gn < N) {
        const float* bp = Bm + (size_t)gk2 * ldb + gn;
        bv = bp[0];
        if (sum4) bv = bv + bp[bStride] + bp[2 * bStride] + bp[3 * bStride];
      }
      Bs[kk2][cc] = bv;
    }
    __syncthreads();
#pragma unroll
    for (int kk = 0; kk < 16; ++kk)
#pragma unroll
      for (int i = 0; i < 4; ++i)
#pragma unroll
        for (int j = 0; j < 4; ++j)
          acc[i][j] += As[ty * 4 + i][kk] * Bs[kk][tx * 4 + j];
    __syncthreads();
  }
#pragma unroll
  for (int i = 0; i < 4; ++i)
#pragma unroll
    for (int j = 0; j < 4; ++j) {
      int gm = m0 + ty * 4 + i, gn = n0 + tx * 4 + j;
      if (gm < M && gn < N) C[(size_t)gm * ldc + gn] = acc[i][j];
    }
}

// ---------------------------------------------------------------------------
// masks_ec: ONE kernel, 256 blocks.
// P1 (all 256): G += (1/B) m2T-chunk^T-stream GEMM (exact dyadic atomics)
// gridbar | P2 (96): Tpart split-K | gridbar | P3 (144): ecpart (B = fixed-order
// 4-chunk sum of Tpart) | gridbar | P4 (144): o_ec = fixed-order sum of ecpart.
// ---------------------------------------------------------------------------
__global__ __launch_bounds__(256) void masks_ec(
    const __bf16* __restrict__ m2T, const __bf16* __restrict__ m1T,
    float* __restrict__ G,
    const float* __restrict__ W2, const float* __restrict__ W1,
    const float* __restrict__ W3,
    float* __restrict__ Tpart, float* __restrict__ ecpart,
    float* __restrict__ o_ec, int* __restrict__ cnt) {
  __shared__ float As[64][17];
  __shared__ float Bs[16][65];
  int tid = threadIdx.x, bid = blockIdx.x;
  // ---- P1: masks GEMM (mapping: iz = bid>>4, ij = bid&15) ----
  {
    int lane = tid & 63, wid = tid >> 6;
    int wr = wid >> 1, wc = wid & 1;
    int ij = bid & 15;
    int ibase = (ij >> 2) * 64, jbase = (ij & 3) * 64;
    size_t b0 = (size_t)(bid >> 4) * 1024 + (lane >> 4) * 8;
    const __bf16* pa0 = m2T + (size_t)(ibase + wr * 32 + (lane & 15)) * 16384 + b0;
    const __bf16* pa1 = pa0 + (size_t)16 * 16384;
    const __bf16* pb0 = m1T + (size_t)(jbase + wc * 32 + (lane & 15)) * 16384 + b0;
    const __bf16* pb1 = pb0 + (size_t)16 * 16384;
    f32x4 acc[2][2] = {};
#pragma unroll 4
    for (int c = 0; c < 32; ++c) {
      bf16x8 a0 = *reinterpret_cast<const bf16x8*>(pa0 + c * 32);
      bf16x8 a1 = *reinterpret_cast<const bf16x8*>(pa1 + c * 32);
      bf16x8 bv0 = *reinterpret_cast<const bf16x8*>(pb0 + c * 32);
      bf16x8 bv1 = *reinterpret_cast<const bf16x8*>(pb1 + c * 32);
      acc[0][0] = mfma_bf16(a0, bv0, acc[0][0]);
      acc[0][1] = mfma_bf16(a0, bv1, acc[0][1]);
      acc[1][0] = mfma_bf16(a1, bv0, acc[1][0]);
      acc[1][1] = mfma_bf16(a1, bv1, acc[1][1]);
    }
    int q4 = (lane >> 4) * 4;
#pragma unroll
    for (int m = 0; m < 2; ++m)
#pragma unroll
      for (int n = 0; n < 2; ++n)
#pragma unroll
        for (int j = 0; j < 4; ++j) {
          int gi = ibase + wr * 32 + m * 16 + q4 + j;
          int gj = jbase + wc * 32 + n * 16 + (lane & 15);
          atomicAdd(&G[(size_t)gi * 256 + gj], acc[m][n][j] * (1.f / 16384.f));
        }
  }
  gridbar(cnt, 256);
  // ---- P2: Tpart[kc] = (W2.*G)[:,kc*64:+64] @ W1l[kc*64:+64,:] ----
  if (bid < 96) {
    int tile = bid >> 2, kc = bid & 3;
    small_body2(As, Bs, tid, W2, G, 256, W1 + 720, 1080, false, 0,
                Tpart + (size_t)kc * 98304, 384, 256, 360,
                kc * 64, kc * 64 + 64, (tile / 6) * 64, (tile % 6) * 64);
  }
  gridbar(cnt, 512);
  // ---- P3: ecpart[kc] = W3[:,kc*64:+64] @ (sum4 Tpart)[kc*64:+64,:] ----
  if (bid < 144) {
    int tile = bid >> 2, kc = bid & 3;
    small_body2(As, Bs, tid, W3, nullptr, 256, Tpart, 384, true, 98304,
                ecpart + (size_t)kc * 129600, 360, 360, 360,
                kc * 64, kc * 64 + 64, (tile / 6) * 64, (tile % 6) * 64);
  }
  gridbar(cnt, 768);
  // ---- P4: o_ec = fixed-order 4-way sum ----
  if (bid < 144) {
    int base = bid * 900;  // 144 * 900 = 129600
    for (int i = tid; i < 900; i += 256) {
      int idx = base + i;
      o_ec[idx] = ecpart[idx] + ecpart[129600 + idx] + ecpart[259200 + idx] +
                  ecpart[388800 + idx];
    }
  }
}

// ---------------------------------------------------------------------------
// Fused: blocks 0..511 -> gemv_p; the LAST gemv block to finish also computes
// znpi1 (fixed-order, single block -> bitwise deterministic).
// blocks 512..767 -> g1 = relu(mc@Wg1^T+bg1) in LDS, then o_zgeo.
// ---------------------------------------------------------------------------
__global__ __launch_bounds__(512) void p_and_g1(
    const float* __restrict__ Wp1, const float* __restrict__ ec,
    const float* __restrict__ bp1, float* __restrict__ p,
    const float* __restrict__ Wp2, const float* __restrict__ bp2,
    float* __restrict__ znpi1, int* __restrict__ pdone,
    const float* __restrict__ mc, const __bf16* __restrict__ Wg1p,
    const float* __restrict__ bg1, const __bf16* __restrict__ Wg2p,
    const float* __restrict__ bg2, float* __restrict__ o_zgeo) {
  __shared__ __bf16 Alds[64][40];
  __shared__ __bf16 g1S[64][264];
  __shared__ float redw[8];
  __shared__ int lastFlag;
  int t = threadIdx.x;
  if (blockIdx.x < 512) {
    int row = blockIdx.x;
    const float4* w = (const float4*)(Wp1 + (size_t)row * 129600);
    const float4* e = (const float4*)ec;
    float s = 0.f;
    for (int i = t; i < 32400; i += 512) {
      float4 a = w[i], b = e[i];
      s += a.x * b.x + a.y * b.y + a.z * b.z + a.w * b.w;
    }
    for (int o = 32; o; o >>= 1) s += __shfl_down(s, o);
    if ((t & 63) == 0) redw[t >> 6] = s;
    __syncthreads();
    if (t == 0) {
      float tot = 0.f;
#pragma unroll
      for (int i = 0; i < 8; ++i) tot += redw[i];
      p[row] = fmaxf(tot + bp1[row], 0.f);
      __threadfence();
      int old = __hip_atomic_fetch_add(pdone, 1, __ATOMIC_ACQ_REL,
                                       __HIP_MEMORY_SCOPE_AGENT);
      lastFlag = (old == 511);
    }
    __syncthreads();
    if (lastFlag) {  // last block: compute znpi1 = Wp2 @ p + bp2 (gemv_z numerics)
      __threadfence();
      int lane = t & 63, wv = t >> 6;
      const float4* pp = (const float4*)p;
      float4 b0 = pp[lane], b1 = pp[lane + 64];
#pragma unroll
      for (int jj = 0; jj < 16; ++jj) {
        int j = wv * 16 + jj;
        const float4* wq = (const float4*)(Wp2 + (size_t)j * 512);
        float4 a0 = wq[lane], a1 = wq[lane + 64];
        float s = a0.x * b0.x + a0.y * b0.y + a0.z * b0.z + a0.w * b0.w +
                  a1.x * b1.x + a1.y * b1.y + a1.z * b1.z + a1.w * b1.w;
        for (int o = 32; o; o >>= 1) s += __shfl_down(s, o);
        if (lane == 0) znpi1[j] = s + bp2[j];
      }
    }
  } else {
    int lane = t & 63, wid = t >> 6;
    int wr = wid >> 2, wc = wid & 3;
    int rowBase = (blockIdx.x - 512) * 64;
    int sr = t >> 3, sc = (t & 7) * 4;
    const float* aSrc = mc + (size_t)(rowBase + sr) * 200;
    int q4 = (lane >> 4) * 4;
    f32x4 acc[2][4] = {};
    for (int kt = 0; kt < 7; ++kt) {
      int gk = kt * 32 + sc;
      bf16x4 w4;
      if (gk < 200) {
        float4 v = *(const float4*)(aSrc + gk);
        w4[0] = (__bf16)v.x; w4[1] = (__bf16)v.y;
        w4[2] = (__bf16)v.z; w4[3] = (__bf16)v.w;
      } else {
        w4[0] = w4[1] = w4[2] = w4[3] = (__bf16)0.f;
      }
      *reinterpret_cast<bf16x4*>(&Alds[sr][sc]) = w4;
      __syncthreads();
      int arow = wr * 32 + (lane & 15), ak = (lane >> 4) * 8;
      bf16x8 a0 = *reinterpret_cast<const bf16x8*>(&Alds[arow][ak]);
      bf16x8 a1 = *reinterpret_cast<const bf16x8*>(&Alds[arow + 16][ak]);
#pragma unroll
      for (int n = 0; n < 4; ++n) {
        bf16x8 bv = ldB(Wg1p, kt, 16, wc * 4 + n, lane);
        acc[0][n] = mfma_bf16(a0, bv, acc[0][n]);
        acc[1][n] = mfma_bf16(a1, bv, acc[1][n]);
      }
      __syncthreads();
    }
#pragma unroll
    for (int m = 0; m < 2; ++m)
#pragma unroll
      for (int n = 0; n < 4; ++n) {
        int col = wc * 64 + n * 16 + (lane & 15);
        float bb = bg1[col];
#pragma unroll
        for (int j = 0; j < 4; ++j) {
          int rl = wr * 32 + m * 16 + q4 + j;
          g1S[rl][col] = (__bf16)fmaxf(acc[m][n][j] + bb, 0.f);
        }
      }
    __syncthreads();
    f32x4 acc2[2][2] = {};
#pragma unroll
    for (int ks = 0; ks < 8; ++ks) {
      int arow = wr * 32 + (lane & 15), ak = ks * 32 + (lane >> 4) * 8;
      bf16x8 a0 = *reinterpret_cast<const bf16x8*>(&g1S[arow][ak]);
      bf16x8 a1 = *reinterpret_cast<const bf16x8*>(&g1S[arow + 16][ak]);
#pragma unroll
      for (int n = 0; n < 2; ++n) {
        bf16x8 bv = ldB(Wg2p, ks, 8, wc * 2 + n, lane);
        acc2[0][n] = mfma_bf16(a0, bv, acc2[0][n]);
        acc2[1][n] = mfma_bf16(a1, bv, acc2[1][n]);
      }
    }
#pragma unroll
    for (int m = 0; m < 2; ++m)
#pragma unroll
      for (int n = 0; n < 2; ++n) {
        int col = wc * 32 + n * 16 + (lane & 15);
        float bb = bg2[col];
#pragma unroll
        for (int j = 0; j < 4; ++j) {
          int row = rowBase + wr * 32 + m * 16 + q4 + j;
          o_zgeo[(size_t)row * 128 + col] = acc2[m][n][j] + bb;
        }
      }
  }
}

// ---------------------------------------------------------------------------
// Tail: zsum = zgeo + znpi1; zn = normalize(zsum); r1 = relu(zn@Wr1^T+br1);
// recon = r1@Wr2^T+br2. One block = 64 rows, 8 waves. zn, r1 live in LDS.
// ---------------------------------------------------------------------------
__global__ __launch_bounds__(512) void mega_tail(
    const float* __restrict__ zgeo, const float* __restrict__ znpi1,
    const __bf16* __restrict__ Wr1p, const float* __restrict__ br1,
    const __bf16* __restrict__ Wr2p, const float* __restrict__ br2,
    float* __restrict__ o_znpi, float* __restrict__ o_zn,
    float* __restrict__ o_rec) {
  __shared__ __bf16 r1S[64][264];
  __shared__ __bf16 znS[64][136];
  __shared__ float znpiS[128];
  int tid = threadIdx.x;
  int lane = tid & 63, wid = tid >> 6;
  int wr = wid >> 2, wc = wid & 3;
  int rowBase = blockIdx.x * 64;
  int q4 = (lane >> 4) * 4;
  if (tid < 128) znpiS[tid] = znpi1[tid];
  __syncthreads();
  {
    int rg = tid >> 5;
    int c4 = (tid & 31) * 4;
    float4 zp = make_float4(znpiS[c4], znpiS[c4 + 1], znpiS[c4 + 2], znpiS[c4 + 3]);
#pragma unroll
    for (int ri = 0; ri < 4; ++ri) {
      int rl = rg + ri * 16;
      int row = rowBase + rl;
      float4 zg = *(const float4*)(zgeo + (size_t)row * 128 + c4);
      float4 zs = make_float4(zg.x + zp.x, zg.y + zp.y, zg.z + zp.z, zg.w + zp.w);
      *(float4*)(o_znpi + (size_t)row * 128 + c4) = zp;
      float ss = zs.x * zs.x + zs.y * zs.y + zs.z * zs.z + zs.w * zs.w;
      ss += __shfl_xor(ss, 1);
      ss += __shfl_xor(ss, 2);
      ss += __shfl_xor(ss, 4);
      ss += __shfl_xor(ss, 8);
      ss += __shfl_xor(ss, 16);
      float rn = 1.f / fmaxf(sqrtf(ss), 1e-12f);
      float4 zn = make_float4(zs.x * rn, zs.y * rn, zs.z * rn, zs.w * rn);
      *(float4*)(o_zn + (size_t)row * 128 + c4) = zn;
      bf16x4 znb;
      znb[0] = (__bf16)zn.x; znb[1] = (__bf16)zn.y;
      znb[2] = (__bf16)zn.z; znb[3] = (__bf16)zn.w;
      *reinterpret_cast<bf16x4*>(&znS[rl][c4]) = znb;
    }
  }
  __syncthreads();
  {
    f32x4 acc[2][4] = {};
#pragma unroll
    for (int ks = 0; ks < 4; ++ks) {
      int arow = wr * 32 + (lane & 15), ak = ks * 32 + (lane >> 4) * 8;
      bf16x8 a0 = *reinterpret_cast<const bf16x8*>(&znS[arow][ak]);
      bf16x8 a1 = *reinterpret_cast<const bf16x8*>(&znS[arow + 16][ak]);
#pragma unroll
      for (int n = 0; n < 4; ++n) {
        bf16x8 bv = ldB(Wr1p, ks, 16, wc * 4 + n, lane);
        acc[0][n] = mfma_bf16(a0, bv, acc[0][n]);
        acc[1][n] = mfma_bf16(a1, bv, acc[1][n]);
      }
    }
#pragma unroll
    for (int m = 0; m < 2; ++m)
#pragma unroll
      for (int n = 0; n < 4; ++n) {
        int col = wc * 64 + n * 16 + (lane & 15);
        float bb = br1[col];
#pragma unroll
        for (int j = 0; j < 4; ++j) {
          int rl = wr * 32 + m * 16 + q4 + j;
          r1S[rl][col] = (__bf16)fmaxf(acc[m][n][j] + bb, 0.f);
        }
      }
  }
  __syncthreads();
  {
    f32x4 acc[2][6] = {};
#pragma unroll
    for (int ks = 0; ks < 8; ++ks) {
      int arow = wr * 32 + (lane & 15), ak = ks * 32 + (lane >> 4) * 8;
      bf16x8 a0 = *reinterpret_cast<const bf16x8*>(&r1S[arow][ak]);
      bf16x8 a1 = *reinterpret_cast<const bf16x8*>(&r1S[arow + 16][ak]);
#pragma unroll
      for (int n = 0; n < 6; ++n) {
        bf16x8 bv = ldB(Wr2p, ks, 24, wc * 6 + n, lane);
        acc[0][n] = mfma_bf16(a0, bv, acc[0][n]);
        acc[1][n] = mfma_bf16(a1, bv, acc[1][n]);
      }
    }
#pragma unroll
    for (int m = 0; m < 2; ++m)
#pragma unroll
      for (int n = 0; n < 6; ++n) {
        int col = wc * 96 + n * 16 + (lane & 15);
        if (col < 360) {
          float bb = br2[col];
#pragma unroll
          for (int j = 0; j < 4; ++j) {
            int rl = wr * 32 + m * 16 + q4 + j;
            o_rec[(size_t)(rowBase + rl) * 360 + col] = acc[m][n][j] + bb;
          }
        }
      }
  }
}

// ---------------------------------------------------------------------------
extern "C" void kernel_launch(void* const* d_in, const int* in_sizes, int n_in,
                              void* d_out, int out_size, void* d_ws,
                              size_t ws_size, hipStream_t stream) {
  (void)in_sizes; (void)n_in; (void)out_size; (void)ws_size;
  const float* x   = (const float*)d_in[0];
  const float* mc  = (const float*)d_in[2];
  const float* W1  = (const float*)d_in[3];  const float* b1  = (const float*)d_in[4];
  const float* W2  = (const float*)d_in[5];  const float* b2  = (const float*)d_in[6];
  const float* W3  = (const float*)d_in[7];
  const float* Wp1 = (const float*)d_in[9];  const float* bp1 = (const float*)d_in[10];
  const float* Wp2 = (const float*)d_in[11]; const float* bp2 = (const float*)d_in[12];
  const float* Wg1 = (const float*)d_in[13]; const float* bg1 = (const float*)d_in[14];
  const float* Wg2 = (const float*)d_in[15]; const float* bg2 = (const float*)d_in[16];
  const float* Wr1 = (const float*)d_in[17]; const float* br1 = (const float*)d_in[18];
  const float* Wr2 = (const float*)d_in[19]; const float* br2 = (const float*)d_in[20];

  float* out = (float*)d_out;
  float* o_znpi = out;                  // (B,128)
  float* o_zgeo = out + 2097152;        // (B,128)
  float* o_zn   = out + 4194304;        // (B,128)
  float* o_ec   = out + 6291456;        // (360,360)
  float* o_rec  = out + 6421056;        // (B,360)

  char* ws = (char*)d_ws;
  __bf16* m1T    = (__bf16*)(ws + 0);            // (256,16384)
  __bf16* m2T    = (__bf16*)(ws + 8388608);      // (256,16384)
  float*  G      = (float*)(ws + 16777216);      // 256x256
  float*  Tpart  = (float*)(ws + 17039360);      // 4 x 256 x 384
  float*  ecpart = (float*)(ws + 18612224);      // 4 x 360 x 360
  float*  p512   = (float*)(ws + 20686848);      // 512
  float*  znpi1  = (float*)(ws + 20688896);      // 128
  __bf16* W1p    = (__bf16*)(ws + 20689920);
  __bf16* W2p    = W1p  + (size_t)544 * 512;
  __bf16* Wg1p   = W2p  + (size_t)128 * 512;
  __bf16* Wg2p   = Wg1p + (size_t)112 * 512;
  __bf16* Wr1p   = Wg2p + (size_t)64 * 512;
  __bf16* Wr2p   = Wr1p + (size_t)64 * 512;
  int*    cnt    = (int*)(ws + 22020096);        // [0]=masks_ec bar, [1]=pdone

  pack_all<<<1136, 64, 0, stream>>>(W1, W2, Wg1, Wg2, Wr1, Wr2,
                                    W1p, W2p, Wg1p, Wg2p, Wr1p, Wr2p, G, cnt);
  h1h2_fused<<<512, 512, 0, stream>>>(x, W1p, b1, W2p, b2, m1T, m2T);
  masks_ec<<<256, 256, 0, stream>>>(m2T, m1T, G, W2, W1, W3, Tpart, ecpart,
                                    o_ec, cnt);
  p_and_g1<<<768, 512, 0, stream>>>(Wp1, o_ec, bp1, p512, Wp2, bp2, znpi1,
                                    cnt + 1, mc, Wg1p, bg1, Wg2p, bg2, o_zgeo);
  mega_tail<<<256, 512, 0, stream>>>(o_zgeo, znpi1, Wr1p, br1, Wr2p, br2,
                                     o_znpi, o_zn, o_rec);
}

// Round 10
// 275.188 us; speedup vs baseline: 1.1323x; 1.1323x over previous
//
#include <hip/hip_runtime.h>

typedef __bf16 bf16x8 __attribute__((ext_vector_type(8)));
typedef __bf16 bf16x4 __attribute__((ext_vector_type(4)));
typedef float  f32x4  __attribute__((ext_vector_type(4)));

__device__ __forceinline__ f32x4 mfma_bf16(bf16x8 a, bf16x8 b, f32x4 c) {
  return __builtin_amdgcn_mfma_f32_16x16x32_bf16(a, b, c, 0, 0, 0);
}
// Packed B-fragment load: Bp[((kt*NT+nt)*64+lane)*8 .. +7]
__device__ __forceinline__ bf16x8 ldB(const __bf16* Bp, int kt, int NT, int nt,
                                      int lane) {
  return *reinterpret_cast<const bf16x8*>(Bp + (((size_t)kt * NT + nt) * 64 + lane) * 8);
}

// Grid barrier -- ONLY for small grids (<=~150 blocks) AFTER uniform light
// phases. R4: 512-blk heavy barriers ~56us each; R9: 256-blk barriers after a
// skewed memory-bound phase ~28us each (3 of them = the +90us regression).
__device__ __forceinline__ void gridbar(int* cnt, int target) {
  __syncthreads();
  if (threadIdx.x == 0) {
    __threadfence();
    __hip_atomic_fetch_add(cnt, 1, __ATOMIC_RELEASE, __HIP_MEMORY_SCOPE_AGENT);
    while (__hip_atomic_load(cnt, __ATOMIC_RELAXED, __HIP_MEMORY_SCOPE_AGENT) < target)
      __builtin_amdgcn_s_sleep(4);
    __threadfence();
  }
  __syncthreads();
}

// ---------------------------------------------------------------------------
// All weight packs in ONE kernel + zero G + zero counters.
// ---------------------------------------------------------------------------
__global__ void pack_all(const float* __restrict__ W1, const float* __restrict__ W2,
                         const float* __restrict__ Wg1, const float* __restrict__ Wg2,
                         const float* __restrict__ Wr1, const float* __restrict__ Wr2,
                         __bf16* __restrict__ W1p, __bf16* __restrict__ W2p,
                         __bf16* __restrict__ Wg1p, __bf16* __restrict__ Wg2p,
                         __bf16* __restrict__ Wr1p, __bf16* __restrict__ Wr2p,
                         float* __restrict__ G, int* __restrict__ cnt) {
  int bx = blockIdx.x;
  int lane = threadIdx.x;
  if (bx >= 1104) {  // zero G (256x256 f32): 32 blocks x 64 thr x 8 float4
    if (bx == 1104 && lane < 2) cnt[lane] = 0;  // [0]=small_split bar, [1]=pdone
    float4* g = (float4*)G;
    int base = (bx - 1104) * 512 + lane;
#pragma unroll
    for (int i = 0; i < 8; ++i) g[base + i * 64] = make_float4(0.f, 0.f, 0.f, 0.f);
    return;
  }
  const float* W; __bf16* out; int N, K, NT, local;
  if (bx < 544)      { W = W1;  out = W1p;  N = 256; K = 1080; NT = 16; local = bx; }
  else if (bx < 672) { W = W2;  out = W2p;  N = 256; K = 256;  NT = 16; local = bx - 544; }
  else if (bx < 784) { W = Wg1; out = Wg1p; N = 256; K = 200;  NT = 16; local = bx - 672; }
  else if (bx < 848) { W = Wg2; out = Wg2p; N = 128; K = 256;  NT = 8;  local = bx - 784; }
  else if (bx < 912) { W = Wr1; out = Wr1p; N = 256; K = 128;  NT = 16; local = bx - 848; }
  else               { W = Wr2; out = Wr2p; N = 360; K = 256;  NT = 24; local = bx - 912; }
  int nt = local % NT, kt = local / NT;
  int n = nt * 16 + (lane & 15);
  int k0 = kt * 32 + (lane >> 4) * 8;
  bf16x8 v;
#pragma unroll
  for (int e = 0; e < 8; ++e) {
    int k = k0 + e;
    float xv = (n < N && k < K) ? W[(size_t)n * K + k] : 0.f;
    v[e] = (__bf16)xv;
  }
  *reinterpret_cast<bf16x8*>(out + ((size_t)local * 64 + lane) * 8) = v;
}

// ---------------------------------------------------------------------------
// Fused surrogate v3 (proven R8): tile 32x256, 8 waves, grid 512 -> 4 waves/SIMD.
// ---------------------------------------------------------------------------
__global__ __launch_bounds__(512) void h1h2_fused(
    const float* __restrict__ x, const __bf16* __restrict__ W1p,
    const float* __restrict__ b1, const __bf16* __restrict__ W2p,
    const float* __restrict__ b2, __bf16* __restrict__ m1T,
    __bf16* __restrict__ m2T) {
  __shared__ __bf16 Alds[32][68];    // 64-wide K-slab, stride 68 (~2-way banks)
  __shared__ __bf16 h1s[32][264];    // relu(h1)
  int tid = threadIdx.x;
  int lane = tid & 63, wid = tid >> 6;
  int wr = wid >> 2, wc = wid & 3;
  int rowBase = blockIdx.x * 32;
  int sr = tid >> 4, sc = (tid & 15) * 4;   // 32 rows x 16 thr x 4 floats
  const float* aSrc = x + (size_t)(rowBase + sr) * 1080;
  f32x4 acc[4] = {};
  float4 c0, c1;
  auto LD = [&](int s, float4& d) {
    int gk = s * 64 + sc;
    d = (gk < 1080) ? *(const float4*)(aSrc + gk) : make_float4(0.f, 0.f, 0.f, 0.f);
  };
  LD(0, c0);
  LD(1, c1);
  for (int s = 0; s < 17; ++s) {
    bf16x4 w4;
    w4[0] = (__bf16)c0.x; w4[1] = (__bf16)c0.y;
    w4[2] = (__bf16)c0.z; w4[3] = (__bf16)c0.w;
    *reinterpret_cast<bf16x4*>(&Alds[sr][sc]) = w4;
    __syncthreads();
    c0 = c1;
    if (s + 2 < 17) LD(s + 2, c1);
    int arow = wr * 16 + (lane & 15);
#pragma unroll
    for (int ks = 0; ks < 2; ++ks) {
      int ak = ks * 32 + (lane >> 4) * 8;
      bf16x8 a0 = *reinterpret_cast<const bf16x8*>(&Alds[arow][ak]);
      int kt = s * 2 + ks;
#pragma unroll
      for (int n = 0; n < 4; ++n) {
        bf16x8 bv = ldB(W1p, kt, 16, wc * 4 + n, lane);
        acc[n] = mfma_bf16(a0, bv, acc[n]);
      }
    }
    __syncthreads();
  }
  int q4 = (lane >> 4) * 4;
#pragma unroll
  for (int n = 0; n < 4; ++n) {
    int col = wc * 64 + n * 16 + (lane & 15);
    float bb = b1[col];
#pragma unroll
    for (int j = 0; j < 4; ++j) {
      int rl = wr * 16 + q4 + j;
      float h = acc[n][j] + bb;
      m1T[(size_t)col * 16384 + rowBase + rl] = (__bf16)(h > 0.f ? 1.f : 0.f);
      h1s[rl][col] = (__bf16)fmaxf(h, 0.f);
    }
  }
  __syncthreads();
  // ---- h2 phase: K=256 from LDS ----
  f32x4 acc2[4] = {};
#pragma unroll
  for (int ks = 0; ks < 8; ++ks) {
    int arow = wr * 16 + (lane & 15), ak = ks * 32 + (lane >> 4) * 8;
    bf16x8 a0 = *reinterpret_cast<const bf16x8*>(&h1s[arow][ak]);
#pragma unroll
    for (int n = 0; n < 4; ++n) {
      bf16x8 bv = ldB(W2p, ks, 16, wc * 4 + n, lane);
      acc2[n] = mfma_bf16(a0, bv, acc2[n]);
    }
  }
#pragma unroll
  for (int n = 0; n < 4; ++n) {
    int col = wc * 64 + n * 16 + (lane & 15);
    float bb = b2[col];
#pragma unroll
    for (int j = 0; j < 4; ++j) {
      int rl = wr * 16 + q4 + j;
      float h = acc2[n][j] + bb;
      m2T[(size_t)col * 16384 + rowBase + rl] = (__bf16)(h > 0.f ? 1.f : 0.f);
    }
  }
}

// ---------------------------------------------------------------------------
// Streaming masks GEMM (separate launch -- R9 lesson: do NOT chain gridbars
// behind this skewed memory-bound phase): G += (1/B) m2^T @ m1 chunks.
// ---------------------------------------------------------------------------
__global__ __launch_bounds__(256) void gemm_masks(
    const __bf16* __restrict__ m2T, const __bf16* __restrict__ m1T,
    float* __restrict__ G) {
  int tid = threadIdx.x;
  int lane = tid & 63, wid = tid >> 6;
  int wr = wid >> 1, wc = wid & 1;
  int ibase = blockIdx.x * 64, jbase = blockIdx.y * 64;
  size_t b0 = (size_t)blockIdx.z * 1024 + (lane >> 4) * 8;
  const __bf16* pa0 = m2T + (size_t)(ibase + wr * 32 + (lane & 15)) * 16384 + b0;
  const __bf16* pa1 = pa0 + (size_t)16 * 16384;
  const __bf16* pb0 = m1T + (size_t)(jbase + wc * 32 + (lane & 15)) * 16384 + b0;
  const __bf16* pb1 = pb0 + (size_t)16 * 16384;
  f32x4 acc[2][2] = {};
#pragma unroll 4
  for (int c = 0; c < 32; ++c) {
    bf16x8 a0 = *reinterpret_cast<const bf16x8*>(pa0 + c * 32);
    bf16x8 a1 = *reinterpret_cast<const bf16x8*>(pa1 + c * 32);
    bf16x8 bv0 = *reinterpret_cast<const bf16x8*>(pb0 + c * 32);
    bf16x8 bv1 = *reinterpret_cast<const bf16x8*>(pb1 + c * 32);
    acc[0][0] = mfma_bf16(a0, bv0, acc[0][0]);
    acc[0][1] = mfma_bf16(a0, bv1, acc[0][1]);
    acc[1][0] = mfma_bf16(a1, bv0, acc[1][0]);
    acc[1][1] = mfma_bf16(a1, bv1, acc[1][1]);
  }
  int q4 = (lane >> 4) * 4;
#pragma unroll
  for (int m = 0; m < 2; ++m)
#pragma unroll
    for (int n = 0; n < 2; ++n)
#pragma unroll
      for (int j = 0; j < 4; ++j) {
        int gi = ibase + wr * 32 + m * 16 + q4 + j;
        int gj = jbase + wc * 32 + n * 16 + (lane & 15);
        atomicAdd(&G[(size_t)gi * 256 + gj], acc[m][n][j] * (1.f / 16384.f));
      }
}

// ---------------------------------------------------------------------------
// 64x64-tile f32 GEMM body over K range [kBeg,kEnd) (multiples of 16, <=256).
// Optional A2 elementwise multiply; optional 4-chunk fixed-order B sum.
// ---------------------------------------------------------------------------
__device__ void small_body2(float (*As)[17], float (*Bs)[65], int t,
                            const float* __restrict__ A, const float* __restrict__ A2,
                            int lda, const float* __restrict__ Bm, int ldb,
                            bool sum4, size_t bStride, float* __restrict__ C,
                            int ldc, int M, int N, int kBeg, int kEnd,
                            int m0, int n0) {
  int tx = t & 15, ty = t >> 4;
  float acc[4][4] = {};
  for (int k0 = kBeg; k0 < kEnd; k0 += 16) {
#pragma unroll
    for (int i = 0; i < 4; ++i) {
      int idx = t * 4 + i;
      int r = idx >> 4, kk = idx & 15;
      int gm = m0 + r, gk = k0 + kk;
      float v = (gm < M) ? A[(size_t)gm * lda + gk] : 0.f;
      if (A2 && gm < M) v *= A2[(size_t)gm * lda + gk];
      As[r][kk] = v;
      int kk2 = idx >> 6, cc = idx & 63;
      int gk2 = k0 + kk2, gn = n0 + cc;
      float bv = 0.f;
      if (gn < N) {
        const float* bp = Bm + (size_t)gk2 * ldb + gn;
        bv = bp[0];
        if (sum4) bv = bv + bp[bStride] + bp[2 * bStride] + bp[3 * bStride];
      }
      Bs[kk2][cc] = bv;
    }
    __syncthreads();
#pragma unroll
    for (int kk = 0; kk < 16; ++kk)
#pragma unroll
      for (int i = 0; i < 4; ++i)
#pragma unroll
        for (int j = 0; j < 4; ++j)
          acc[i][j] += As[ty * 4 + i][kk] * Bs[kk][tx * 4 + j];
    __syncthreads();
  }
#pragma unroll
  for (int i = 0; i < 4; ++i)
#pragma unroll
    for (int j = 0; j < 4; ++j) {
      int gm = m0 + ty * 4 + i, gn = n0 + tx * 4 + j;
      if (gm < M && gn < N) C[(size_t)gm * ldc + gn] = acc[i][j];
    }
}

// ---------------------------------------------------------------------------
// ec chain, split-K, ONE kernel (144 blocks, uniform light phases -- proven R8).
// ---------------------------------------------------------------------------
__global__ __launch_bounds__(256) void small_split(
    const float* __restrict__ W2, const float* __restrict__ G,
    const float* __restrict__ W1, const float* __restrict__ W3,
    float* __restrict__ Tpart, float* __restrict__ ecpart,
    float* __restrict__ o_ec, int* __restrict__ cnt) {
  __shared__ float As[64][17];
  __shared__ float Bs[16][65];
  int t = threadIdx.x, bid = blockIdx.x;
  if (bid < 96) {
    int tile = bid >> 2, kc = bid & 3;
    small_body2(As, Bs, t, W2, G, 256, W1 + 720, 1080, false, 0,
                Tpart + (size_t)kc * 98304, 384, 256, 360,
                kc * 64, kc * 64 + 64, (tile / 6) * 64, (tile % 6) * 64);
  }
  gridbar(cnt, 144);
  {
    int tile = bid >> 2, kc = bid & 3;  // 144 = 36 tiles x 4 kc
    small_body2(As, Bs, t, W3, nullptr, 256, Tpart, 384, true, 98304,
                ecpart + (size_t)kc * 129600, 360, 360, 360,
                kc * 64, kc * 64 + 64, (tile / 6) * 64, (tile % 6) * 64);
  }
  gridbar(cnt, 288);
  {
    int base = bid * 900;  // 144 * 900 = 129600
    for (int i = t; i < 900; i += 256) {
      int idx = base + i;
      o_ec[idx] = ecpart[idx] + ecpart[129600 + idx] + ecpart[259200 + idx] +
                  ecpart[388800 + idx];
    }
  }
}

// ---------------------------------------------------------------------------
// Fused: blocks 0..511 -> gemv_p; LAST gemv block also computes znpi1
// (single block, fixed order -> bitwise deterministic; kills gemv_z launch).
// blocks 512..767 -> g1 = relu(mc@Wg1^T+bg1) in LDS, then o_zgeo.
// ---------------------------------------------------------------------------
__global__ __launch_bounds__(512) void p_and_g1(
    const float* __restrict__ Wp1, const float* __restrict__ ec,
    const float* __restrict__ bp1, float* __restrict__ p,
    const float* __restrict__ Wp2, const float* __restrict__ bp2,
    float* __restrict__ znpi1, int* __restrict__ pdone,
    const float* __restrict__ mc, const __bf16* __restrict__ Wg1p,
    const float* __restrict__ bg1, const __bf16* __restrict__ Wg2p,
    const float* __restrict__ bg2, float* __restrict__ o_zgeo) {
  __shared__ __bf16 Alds[64][40];
  __shared__ __bf16 g1S[64][264];
  __shared__ float redw[8];
  __shared__ int lastFlag;
  int t = threadIdx.x;
  if (blockIdx.x < 512) {
    int row = blockIdx.x;
    const float4* w = (const float4*)(Wp1 + (size_t)row * 129600);
    const float4* e = (const float4*)ec;
    float s = 0.f;
    for (int i = t; i < 32400; i += 512) {
      float4 a = w[i], b = e[i];
      s += a.x * b.x + a.y * b.y + a.z * b.z + a.w * b.w;
    }
    for (int o = 32; o; o >>= 1) s += __shfl_down(s, o);
    if ((t & 63) == 0) redw[t >> 6] = s;
    __syncthreads();
    if (t == 0) {
      float tot = 0.f;
#pragma unroll
      for (int i = 0; i < 8; ++i) tot += redw[i];
      p[row] = fmaxf(tot + bp1[row], 0.f);
      __threadfence();
      int old = __hip_atomic_fetch_add(pdone, 1, __ATOMIC_ACQ_REL,
                                       __HIP_MEMORY_SCOPE_AGENT);
      lastFlag = (old == 511);
    }
    __syncthreads();
    if (lastFlag) {  // last block: znpi1 = Wp2 @ p + bp2 (gemv_z numerics)
      __threadfence();
      int lane = t & 63, wv = t >> 6;
      const float4* pp = (const float4*)p;
      float4 b0 = pp[lane], b1 = pp[lane + 64];
#pragma unroll
      for (int jj = 0; jj < 16; ++jj) {
        int j = wv * 16 + jj;
        const float4* wq = (const float4*)(Wp2 + (size_t)j * 512);
        float4 a0 = wq[lane], a1 = wq[lane + 64];
        float s = a0.x * b0.x + a0.y * b0.y + a0.z * b0.z + a0.w * b0.w +
                  a1.x * b1.x + a1.y * b1.y + a1.z * b1.z + a1.w * b1.w;
        for (int o = 32; o; o >>= 1) s += __shfl_down(s, o);
        if (lane == 0) znpi1[j] = s + bp2[j];
      }
    }
  } else {
    int lane = t & 63, wid = t >> 6;
    int wr = wid >> 2, wc = wid & 3;
    int rowBase = (blockIdx.x - 512) * 64;
    int sr = t >> 3, sc = (t & 7) * 4;
    const float* aSrc = mc + (size_t)(rowBase + sr) * 200;
    int q4 = (lane >> 4) * 4;
    f32x4 acc[2][4] = {};
    for (int kt = 0; kt < 7; ++kt) {
      int gk = kt * 32 + sc;
      bf16x4 w4;
      if (gk < 200) {
        float4 v = *(const float4*)(aSrc + gk);
        w4[0] = (__bf16)v.x; w4[1] = (__bf16)v.y;
        w4[2] = (__bf16)v.z; w4[3] = (__bf16)v.w;
      } else {
        w4[0] = w4[1] = w4[2] = w4[3] = (__bf16)0.f;
      }
      *reinterpret_cast<bf16x4*>(&Alds[sr][sc]) = w4;
      __syncthreads();
      int arow = wr * 32 + (lane & 15), ak = (lane >> 4) * 8;
      bf16x8 a0 = *reinterpret_cast<const bf16x8*>(&Alds[arow][ak]);
      bf16x8 a1 = *reinterpret_cast<const bf16x8*>(&Alds[arow + 16][ak]);
#pragma unroll
      for (int n = 0; n < 4; ++n) {
        bf16x8 bv = ldB(Wg1p, kt, 16, wc * 4 + n, lane);
        acc[0][n] = mfma_bf16(a0, bv, acc[0][n]);
        acc[1][n] = mfma_bf16(a1, bv, acc[1][n]);
      }
      __syncthreads();
    }
#pragma unroll
    for (int m = 0; m < 2; ++m)
#pragma unroll
      for (int n = 0; n < 4; ++n) {
        int col = wc * 64 + n * 16 + (lane & 15);
        float bb = bg1[col];
#pragma unroll
        for (int j = 0; j < 4; ++j) {
          int rl = wr * 32 + m * 16 + q4 + j;
          g1S[rl][col] = (__bf16)fmaxf(acc[m][n][j] + bb, 0.f);
        }
      }
    __syncthreads();
    f32x4 acc2[2][2] = {};
#pragma unroll
    for (int ks = 0; ks < 8; ++ks) {
      int arow = wr * 32 + (lane & 15), ak = ks * 32 + (lane >> 4) * 8;
      bf16x8 a0 = *reinterpret_cast<const bf16x8*>(&g1S[arow][ak]);
      bf16x8 a1 = *reinterpret_cast<const bf16x8*>(&g1S[arow + 16][ak]);
#pragma unroll
      for (int n = 0; n < 2; ++n) {
        bf16x8 bv = ldB(Wg2p, ks, 8, wc * 2 + n, lane);
        acc2[0][n] = mfma_bf16(a0, bv, acc2[0][n]);
        acc2[1][n] = mfma_bf16(a1, bv, acc2[1][n]);
      }
    }
#pragma unroll
    for (int m = 0; m < 2; ++m)
#pragma unroll
      for (int n = 0; n < 2; ++n) {
        int col = wc * 32 + n * 16 + (lane & 15);
        float bb = bg2[col];
#pragma unroll
        for (int j = 0; j < 4; ++j) {
          int row = rowBase + wr * 32 + m * 16 + q4 + j;
          o_zgeo[(size_t)row * 128 + col] = acc2[m][n][j] + bb;
        }
      }
  }
}

// ---------------------------------------------------------------------------
// Tail: zsum = zgeo + znpi1; zn = normalize(zsum); r1 = relu(zn@Wr1^T+br1);
// recon = r1@Wr2^T+br2. One block = 64 rows, 8 waves. zn, r1 live in LDS.
// ---------------------------------------------------------------------------
__global__ __launch_bounds__(512) void mega_tail(
    const float* __restrict__ zgeo, const float* __restrict__ znpi1,
    const __bf16* __restrict__ Wr1p, const float* __restrict__ br1,
    const __bf16* __restrict__ Wr2p, const float* __restrict__ br2,
    float* __restrict__ o_znpi, float* __restrict__ o_zn,
    float* __restrict__ o_rec) {
  __shared__ __bf16 r1S[64][264];
  __shared__ __bf16 znS[64][136];
  __shared__ float znpiS[128];
  int tid = threadIdx.x;
  int lane = tid & 63, wid = tid >> 6;
  int wr = wid >> 2, wc = wid & 3;
  int rowBase = blockIdx.x * 64;
  int q4 = (lane >> 4) * 4;
  if (tid < 128) znpiS[tid] = znpi1[tid];
  __syncthreads();
  {
    int rg = tid >> 5;
    int c4 = (tid & 31) * 4;
    float4 zp = make_float4(znpiS[c4], znpiS[c4 + 1], znpiS[c4 + 2], znpiS[c4 + 3]);
#pragma unroll
    for (int ri = 0; ri < 4; ++ri) {
      int rl = rg + ri * 16;
      int row = rowBase + rl;
      float4 zg = *(const float4*)(zgeo + (size_t)row * 128 + c4);
      float4 zs = make_float4(zg.x + zp.x, zg.y + zp.y, zg.z + zp.z, zg.w + zp.w);
      *(float4*)(o_znpi + (size_t)row * 128 + c4) = zp;
      float ss = zs.x * zs.x + zs.y * zs.y + zs.z * zs.z + zs.w * zs.w;
      ss += __shfl_xor(ss, 1);
      ss += __shfl_xor(ss, 2);
      ss += __shfl_xor(ss, 4);
      ss += __shfl_xor(ss, 8);
      ss += __shfl_xor(ss, 16);
      float rn = 1.f / fmaxf(sqrtf(ss), 1e-12f);
      float4 zn = make_float4(zs.x * rn, zs.y * rn, zs.z * rn, zs.w * rn);
      *(float4*)(o_zn + (size_t)row * 128 + c4) = zn;
      bf16x4 znb;
      znb[0] = (__bf16)zn.x; znb[1] = (__bf16)zn.y;
      znb[2] = (__bf16)zn.z; znb[3] = (__bf16)zn.w;
      *reinterpret_cast<bf16x4*>(&znS[rl][c4]) = znb;
    }
  }
  __syncthreads();
  {
    f32x4 acc[2][4] = {};
#pragma unroll
    for (int ks = 0; ks < 4; ++ks) {
      int arow = wr * 32 + (lane & 15), ak = ks * 32 + (lane >> 4) * 8;
      bf16x8 a0 = *reinterpret_cast<const bf16x8*>(&znS[arow][ak]);
      bf16x8 a1 = *reinterpret_cast<const bf16x8*>(&znS[arow + 16][ak]);
#pragma unroll
      for (int n = 0; n < 4; ++n) {
        bf16x8 bv = ldB(Wr1p, ks, 16, wc * 4 + n, lane);
        acc[0][n] = mfma_bf16(a0, bv, acc[0][n]);
        acc[1][n] = mfma_bf16(a1, bv, acc[1][n]);
      }
    }
#pragma unroll
    for (int m = 0; m < 2; ++m)
#pragma unroll
      for (int n = 0; n < 4; ++n) {
        int col = wc * 64 + n * 16 + (lane & 15);
        float bb = br1[col];
#pragma unroll
        for (int j = 0; j < 4; ++j) {
          int rl = wr * 32 + m * 16 + q4 + j;
          r1S[rl][col] = (__bf16)fmaxf(acc[m][n][j] + bb, 0.f);
        }
      }
  }
  __syncthreads();
  {
    f32x4 acc[2][6] = {};
#pragma unroll
    for (int ks = 0; ks < 8; ++ks) {
      int arow = wr * 32 + (lane & 15), ak = ks * 32 + (lane >> 4) * 8;
      bf16x8 a0 = *reinterpret_cast<const bf16x8*>(&r1S[arow][ak]);
      bf16x8 a1 = *reinterpret_cast<const bf16x8*>(&r1S[arow + 16][ak]);
#pragma unroll
      for (int n = 0; n < 6; ++n) {
        bf16x8 bv = ldB(Wr2p, ks, 24, wc * 6 + n, lane);
        acc[0][n] = mfma_bf16(a0, bv, acc[0][n]);
        acc[1][n] = mfma_bf16(a1, bv, acc[1][n]);
      }
    }
#pragma unroll
    for (int m = 0; m < 2; ++m)
#pragma unroll
      for (int n = 0; n < 6; ++n) {
        int col = wc * 96 + n * 16 + (lane & 15);
        if (col < 360) {
          float bb = br2[col];
#pragma unroll
          for (int j = 0; j < 4; ++j) {
            int rl = wr * 32 + m * 16 + q4 + j;
            o_rec[(size_t)(rowBase + rl) * 360 + col] = acc[m][n][j] + bb;
          }
        }
      }
  }
}

// ---------------------------------------------------------------------------
extern "C" void kernel_launch(void* const* d_in, const int* in_sizes, int n_in,
                              void* d_out, int out_size, void* d_ws,
                              size_t ws_size, hipStream_t stream) {
  (void)in_sizes; (void)n_in; (void)out_size; (void)ws_size;
  const float* x   = (const float*)d_in[0];
  const float* mc  = (const float*)d_in[2];
  const float* W1  = (const float*)d_in[3];  const float* b1  = (const float*)d_in[4];
  const float* W2  = (const float*)d_in[5];  const float* b2  = (const float*)d_in[6];
  const float* W3  = (const float*)d_in[7];
  const float* Wp1 = (const float*)d_in[9];  const float* bp1 = (const float*)d_in[10];
  const float* Wp2 = (const float*)d_in[11]; const float* bp2 = (const float*)d_in[12];
  const float* Wg1 = (const float*)d_in[13]; const float* bg1 = (const float*)d_in[14];
  const float* Wg2 = (const float*)d_in[15]; const float* bg2 = (const float*)d_in[16];
  const float* Wr1 = (const float*)d_in[17]; const float* br1 = (const float*)d_in[18];
  const float* Wr2 = (const float*)d_in[19]; const float* br2 = (const float*)d_in[20];

  float* out = (float*)d_out;
  float* o_znpi = out;                  // (B,128)
  float* o_zgeo = out + 2097152;        // (B,128)
  float* o_zn   = out + 4194304;        // (B,128)
  float* o_ec   = out + 6291456;        // (360,360)
  float* o_rec  = out + 6421056;        // (B,360)

  char* ws = (char*)d_ws;
  __bf16* m1T    = (__bf16*)(ws + 0);            // (256,16384)
  __bf16* m2T    = (__bf16*)(ws + 8388608);      // (256,16384)
  float*  G      = (float*)(ws + 16777216);      // 256x256
  float*  Tpart  = (float*)(ws + 17039360);      // 4 x 256 x 384
  float*  ecpart = (float*)(ws + 18612224);      // 4 x 360 x 360
  float*  p512   = (float*)(ws + 20686848);      // 512
  float*  znpi1  = (float*)(ws + 20688896);      // 128
  __bf16* W1p    = (__bf16*)(ws + 20689920);
  __bf16* W2p    = W1p  + (size_t)544 * 512;
  __bf16* Wg1p   = W2p  + (size_t)128 * 512;
  __bf16* Wg2p   = Wg1p + (size_t)112 * 512;
  __bf16* Wr1p   = Wg2p + (size_t)64 * 512;
  __bf16* Wr2p   = Wr1p + (size_t)64 * 512;
  int*    cnt    = (int*)(ws + 22020096);        // [0]=small_split bar, [1]=pdone

  pack_all<<<1136, 64, 0, stream>>>(W1, W2, Wg1, Wg2, Wr1, Wr2,
                                    W1p, W2p, Wg1p, Wg2p, Wr1p, Wr2p, G, cnt);
  h1h2_fused<<<512, 512, 0, stream>>>(x, W1p, b1, W2p, b2, m1T, m2T);
  gemm_masks<<<dim3(4, 4, 16), 256, 0, stream>>>(m2T, m1T, G);
  small_split<<<144, 256, 0, stream>>>(W2, G, W1, W3, Tpart, ecpart, o_ec,
                                       cnt);
  p_and_g1<<<768, 512, 0, stream>>>(Wp1, o_ec, bp1, p512, Wp2, bp2, znpi1,
                                    cnt + 1, mc, Wg1p, bg1, Wg2p, bg2, o_zgeo);
  mega_tail<<<256, 512, 0, stream>>>(o_zgeo, znpi1, Wr1p, br1, Wr2p, br2,
                                     o_znpi, o_zn, o_rec);
}

// Round 11
// 244.582 us; speedup vs baseline: 1.2739x; 1.1251x over previous
//
#include <hip/hip_runtime.h>

typedef __bf16 bf16x8 __attribute__((ext_vector_type(8)));
typedef __bf16 bf16x4 __attribute__((ext_vector_type(4)));
typedef float  f32x4  __attribute__((ext_vector_type(4)));

__device__ __forceinline__ f32x4 mfma_bf16(bf16x8 a, bf16x8 b, f32x4 c) {
  return __builtin_amdgcn_mfma_f32_16x16x32_bf16(a, b, c, 0, 0, 0);
}
// Packed B-fragment load: Bp[((kt*NT+nt)*64+lane)*8 .. +7]
__device__ __forceinline__ bf16x8 ldB(const __bf16* Bp, int kt, int NT, int nt,
                                      int lane) {
  return *reinterpret_cast<const bf16x8*>(Bp + (((size_t)kt * NT + nt) * 64 + lane) * 8);
}

// Grid barrier -- ONLY small grids (<=~150 blocks) after uniform light phases.
// R4: 512-blk heavy barriers ~56us each. R9: 256-blk barriers after skewed
// memory phase ~28us each. R10: even per-block threadfence+atomic release in a
// 512-blk HBM-streaming kernel costs ~50us. Keep device-scope sync OUT of
// streaming kernels entirely.
__device__ __forceinline__ void gridbar(int* cnt, int target) {
  __syncthreads();
  if (threadIdx.x == 0) {
    __threadfence();
    __hip_atomic_fetch_add(cnt, 1, __ATOMIC_RELEASE, __HIP_MEMORY_SCOPE_AGENT);
    while (__hip_atomic_load(cnt, __ATOMIC_RELAXED, __HIP_MEMORY_SCOPE_AGENT) < target)
      __builtin_amdgcn_s_sleep(4);
    __threadfence();
  }
  __syncthreads();
}

// ---------------------------------------------------------------------------
// All weight packs in ONE kernel + zero G + zero counters.
// ---------------------------------------------------------------------------
__global__ void pack_all(const float* __restrict__ W1, const float* __restrict__ W2,
                         const float* __restrict__ Wg1, const float* __restrict__ Wg2,
                         const float* __restrict__ Wr1, const float* __restrict__ Wr2,
                         __bf16* __restrict__ W1p, __bf16* __restrict__ W2p,
                         __bf16* __restrict__ Wg1p, __bf16* __restrict__ Wg2p,
                         __bf16* __restrict__ Wr1p, __bf16* __restrict__ Wr2p,
                         float* __restrict__ G, int* __restrict__ cnt) {
  int bx = blockIdx.x;
  int lane = threadIdx.x;
  if (bx >= 1104) {  // zero G (256x256 f32): 32 blocks x 64 thr x 8 float4
    if (bx == 1104 && lane < 2) cnt[lane] = 0;  // [0]=small_split bar
    float4* g = (float4*)G;
    int base = (bx - 1104) * 512 + lane;
#pragma unroll
    for (int i = 0; i < 8; ++i) g[base + i * 64] = make_float4(0.f, 0.f, 0.f, 0.f);
    return;
  }
  const float* W; __bf16* out; int N, K, NT, local;
  if (bx < 544)      { W = W1;  out = W1p;  N = 256; K = 1080; NT = 16; local = bx; }
  else if (bx < 672) { W = W2;  out = W2p;  N = 256; K = 256;  NT = 16; local = bx - 544; }
  else if (bx < 784) { W = Wg1; out = Wg1p; N = 256; K = 200;  NT = 16; local = bx - 672; }
  else if (bx < 848) { W = Wg2; out = Wg2p; N = 128; K = 256;  NT = 8;  local = bx - 784; }
  else if (bx < 912) { W = Wr1; out = Wr1p; N = 256; K = 128;  NT = 16; local = bx - 848; }
  else               { W = Wr2; out = Wr2p; N = 360; K = 256;  NT = 24; local = bx - 912; }
  int nt = local % NT, kt = local / NT;
  int n = nt * 16 + (lane & 15);
  int k0 = kt * 32 + (lane >> 4) * 8;
  bf16x8 v;
#pragma unroll
  for (int e = 0; e < 8; ++e) {
    int k = k0 + e;
    float xv = (n < N && k < K) ? W[(size_t)n * K + k] : 0.f;
    v[e] = (__bf16)xv;
  }
  *reinterpret_cast<bf16x8*>(out + ((size_t)local * 64 + lane) * 8) = v;
}

// ---------------------------------------------------------------------------
// Fused surrogate v3 (proven R8): tile 32x256, 8 waves, grid 512 -> 4 waves/SIMD.
// ---------------------------------------------------------------------------
__global__ __launch_bounds__(512) void h1h2_fused(
    const float* __restrict__ x, const __bf16* __restrict__ W1p,
    const float* __restrict__ b1, const __bf16* __restrict__ W2p,
    const float* __restrict__ b2, __bf16* __restrict__ m1T,
    __bf16* __restrict__ m2T) {
  __shared__ __bf16 Alds[32][68];    // 64-wide K-slab, stride 68 (~2-way banks)
  __shared__ __bf16 h1s[32][264];    // relu(h1)
  int tid = threadIdx.x;
  int lane = tid & 63, wid = tid >> 6;
  int wr = wid >> 2, wc = wid & 3;
  int rowBase = blockIdx.x * 32;
  int sr = tid >> 4, sc = (tid & 15) * 4;   // 32 rows x 16 thr x 4 floats
  const float* aSrc = x + (size_t)(rowBase + sr) * 1080;
  f32x4 acc[4] = {};
  float4 c0, c1;
  auto LD = [&](int s, float4& d) {
    int gk = s * 64 + sc;
    d = (gk < 1080) ? *(const float4*)(aSrc + gk) : make_float4(0.f, 0.f, 0.f, 0.f);
  };
  LD(0, c0);
  LD(1, c1);
  for (int s = 0; s < 17; ++s) {
    bf16x4 w4;
    w4[0] = (__bf16)c0.x; w4[1] = (__bf16)c0.y;
    w4[2] = (__bf16)c0.z; w4[3] = (__bf16)c0.w;
    *reinterpret_cast<bf16x4*>(&Alds[sr][sc]) = w4;
    __syncthreads();
    c0 = c1;
    if (s + 2 < 17) LD(s + 2, c1);
    int arow = wr * 16 + (lane & 15);
#pragma unroll
    for (int ks = 0; ks < 2; ++ks) {
      int ak = ks * 32 + (lane >> 4) * 8;
      bf16x8 a0 = *reinterpret_cast<const bf16x8*>(&Alds[arow][ak]);
      int kt = s * 2 + ks;
#pragma unroll
      for (int n = 0; n < 4; ++n) {
        bf16x8 bv = ldB(W1p, kt, 16, wc * 4 + n, lane);
        acc[n] = mfma_bf16(a0, bv, acc[n]);
      }
    }
    __syncthreads();
  }
  int q4 = (lane >> 4) * 4;
#pragma unroll
  for (int n = 0; n < 4; ++n) {
    int col = wc * 64 + n * 16 + (lane & 15);
    float bb = b1[col];
#pragma unroll
    for (int j = 0; j < 4; ++j) {
      int rl = wr * 16 + q4 + j;
      float h = acc[n][j] + bb;
      m1T[(size_t)col * 16384 + rowBase + rl] = (__bf16)(h > 0.f ? 1.f : 0.f);
      h1s[rl][col] = (__bf16)fmaxf(h, 0.f);
    }
  }
  __syncthreads();
  // ---- h2 phase: K=256 from LDS ----
  f32x4 acc2[4] = {};
#pragma unroll
  for (int ks = 0; ks < 8; ++ks) {
    int arow = wr * 16 + (lane & 15), ak = ks * 32 + (lane >> 4) * 8;
    bf16x8 a0 = *reinterpret_cast<const bf16x8*>(&h1s[arow][ak]);
#pragma unroll
    for (int n = 0; n < 4; ++n) {
      bf16x8 bv = ldB(W2p, ks, 16, wc * 4 + n, lane);
      acc2[n] = mfma_bf16(a0, bv, acc2[n]);
    }
  }
#pragma unroll
  for (int n = 0; n < 4; ++n) {
    int col = wc * 64 + n * 16 + (lane & 15);
    float bb = b2[col];
#pragma unroll
    for (int j = 0; j < 4; ++j) {
      int rl = wr * 16 + q4 + j;
      float h = acc2[n][j] + bb;
      m2T[(size_t)col * 16384 + rowBase + rl] = (__bf16)(h > 0.f ? 1.f : 0.f);
    }
  }
}

// ---------------------------------------------------------------------------
// Streaming masks GEMM: G += (1/B) m2^T @ m1 chunks. Exact dyadic atomics.
// ---------------------------------------------------------------------------
__global__ __launch_bounds__(256) void gemm_masks(
    const __bf16* __restrict__ m2T, const __bf16* __restrict__ m1T,
    float* __restrict__ G) {
  int tid = threadIdx.x;
  int lane = tid & 63, wid = tid >> 6;
  int wr = wid >> 1, wc = wid & 1;
  int ibase = blockIdx.x * 64, jbase = blockIdx.y * 64;
  size_t b0 = (size_t)blockIdx.z * 1024 + (lane >> 4) * 8;
  const __bf16* pa0 = m2T + (size_t)(ibase + wr * 32 + (lane & 15)) * 16384 + b0;
  const __bf16* pa1 = pa0 + (size_t)16 * 16384;
  const __bf16* pb0 = m1T + (size_t)(jbase + wc * 32 + (lane & 15)) * 16384 + b0;
  const __bf16* pb1 = pb0 + (size_t)16 * 16384;
  f32x4 acc[2][2] = {};
#pragma unroll 4
  for (int c = 0; c < 32; ++c) {
    bf16x8 a0 = *reinterpret_cast<const bf16x8*>(pa0 + c * 32);
    bf16x8 a1 = *reinterpret_cast<const bf16x8*>(pa1 + c * 32);
    bf16x8 bv0 = *reinterpret_cast<const bf16x8*>(pb0 + c * 32);
    bf16x8 bv1 = *reinterpret_cast<const bf16x8*>(pb1 + c * 32);
    acc[0][0] = mfma_bf16(a0, bv0, acc[0][0]);
    acc[0][1] = mfma_bf16(a0, bv1, acc[0][1]);
    acc[1][0] = mfma_bf16(a1, bv0, acc[1][0]);
    acc[1][1] = mfma_bf16(a1, bv1, acc[1][1]);
  }
  int q4 = (lane >> 4) * 4;
#pragma unroll
  for (int m = 0; m < 2; ++m)
#pragma unroll
    for (int n = 0; n < 2; ++n)
#pragma unroll
      for (int j = 0; j < 4; ++j) {
        int gi = ibase + wr * 32 + m * 16 + q4 + j;
        int gj = jbase + wc * 32 + n * 16 + (lane & 15);
        atomicAdd(&G[(size_t)gi * 256 + gj], acc[m][n][j] * (1.f / 16384.f));
      }
}

// ---------------------------------------------------------------------------
// 64x64-tile f32 GEMM body over K range [kBeg,kEnd).
// ---------------------------------------------------------------------------
__device__ void small_body2(float (*As)[17], float (*Bs)[65], int t,
                            const float* __restrict__ A, const float* __restrict__ A2,
                            int lda, const float* __restrict__ Bm, int ldb,
                            bool sum4, size_t bStride, float* __restrict__ C,
                            int ldc, int M, int N, int kBeg, int kEnd,
                            int m0, int n0) {
  int tx = t & 15, ty = t >> 4;
  float acc[4][4] = {};
  for (int k0 = kBeg; k0 < kEnd; k0 += 16) {
#pragma unroll
    for (int i = 0; i < 4; ++i) {
      int idx = t * 4 + i;
      int r = idx >> 4, kk = idx & 15;
      int gm = m0 + r, gk = k0 + kk;
      float v = (gm < M) ? A[(size_t)gm * lda + gk] : 0.f;
      if (A2 && gm < M) v *= A2[(size_t)gm * lda + gk];
      As[r][kk] = v;
      int kk2 = idx >> 6, cc = idx & 63;
      int gk2 = k0 + kk2, gn = n0 + cc;
      float bv = 0.f;
      if (gn < N) {
        const float* bp = Bm + (size_t)gk2 * ldb + gn;
        bv = bp[0];
        if (sum4) bv = bv + bp[bStride] + bp[2 * bStride] + bp[3 * bStride];
      }
      Bs[kk2][cc] = bv;
    }
    __syncthreads();
#pragma unroll
    for (int kk = 0; kk < 16; ++kk)
#pragma unroll
      for (int i = 0; i < 4; ++i)
#pragma unroll
        for (int j = 0; j < 4; ++j)
          acc[i][j] += As[ty * 4 + i][kk] * Bs[kk][tx * 4 + j];
    __syncthreads();
  }
#pragma unroll
  for (int i = 0; i < 4; ++i)
#pragma unroll
    for (int j = 0; j < 4; ++j) {
      int gm = m0 + ty * 4 + i, gn = n0 + tx * 4 + j;
      if (gm < M && gn < N) C[(size_t)gm * ldc + gn] = acc[i][j];
    }
}

// ---------------------------------------------------------------------------
// ec chain, split-K, ONE kernel (144 blocks, uniform light phases -- proven R8).
// ---------------------------------------------------------------------------
__global__ __launch_bounds__(256) void small_split(
    const float* __restrict__ W2, const float* __restrict__ G,
    const float* __restrict__ W1, const float* __restrict__ W3,
    float* __restrict__ Tpart, float* __restrict__ ecpart,
    float* __restrict__ o_ec, int* __restrict__ cnt) {
  __shared__ float As[64][17];
  __shared__ float Bs[16][65];
  int t = threadIdx.x, bid = blockIdx.x;
  if (bid < 96) {
    int tile = bid >> 2, kc = bid & 3;
    small_body2(As, Bs, t, W2, G, 256, W1 + 720, 1080, false, 0,
                Tpart + (size_t)kc * 98304, 384, 256, 360,
                kc * 64, kc * 64 + 64, (tile / 6) * 64, (tile % 6) * 64);
  }
  gridbar(cnt, 144);
  {
    int tile = bid >> 2, kc = bid & 3;  // 144 = 36 tiles x 4 kc
    small_body2(As, Bs, t, W3, nullptr, 256, Tpart, 384, true, 98304,
                ecpart + (size_t)kc * 129600, 360, 360, 360,
                kc * 64, kc * 64 + 64, (tile / 6) * 64, (tile % 6) * 64);
  }
  gridbar(cnt, 288);
  {
    int base = bid * 900;  // 144 * 900 = 129600
    for (int i = t; i < 900; i += 256) {
      int idx = base + i;
      o_ec[idx] = ecpart[idx] + ecpart[129600 + idx] + ecpart[259200 + idx] +
                  ecpart[388800 + idx];
    }
  }
}

// ---------------------------------------------------------------------------
// p_and_g1 v2 -- R10 profile: old 1-row/block gemv ran at 1 TB/s (148us),
// latency/L3-bound because 512 blocks each re-read the full 518KB ec (265MB
// redundant), evicting it from per-XCD L2. Fix: 128 blocks x 4 rows, ec staged
// once per block through 32KB LDS chunks (ec traffic 265MB -> 66MB, L2-served);
// Wp1 stays a coalesced HBM stream. One wave-pair per row; halves combined via
// 8-float LDS reduce (fixed order). No device-scope fences/atomics here.
// blocks 0..127: gemv arm. blocks 128..383: g1 arm (proven R8 code).
// ---------------------------------------------------------------------------
__global__ __launch_bounds__(512) void p_and_g1(
    const float* __restrict__ Wp1, const float* __restrict__ ec,
    const float* __restrict__ bp1, float* __restrict__ p,
    const float* __restrict__ mc, const __bf16* __restrict__ Wg1p,
    const float* __restrict__ bg1, const __bf16* __restrict__ Wg2p,
    const float* __restrict__ bg2, float* __restrict__ o_zgeo) {
  __shared__ __align__(16) char SM[39424];
  int t = threadIdx.x;
  if (blockIdx.x < 128) {
    float4* eS = (float4*)SM;              // 2048 float4 = 32 KB
    float* sred = (float*)(SM + 32768);    // 8 floats
    int lane = t & 63, w = t >> 6;
    int row = blockIdx.x * 4 + (w & 3);
    int half = w >> 2;
    const float4* wrow = (const float4*)(Wp1 + (size_t)row * 129600);
    const float4* e4 = (const float4*)ec;
    float s = 0.f;
    for (int c = 0; c < 15; ++c) {         // full chunks: f4 [c*2048, +2048)
      int base = c * 2048;
      __syncthreads();                     // previous chunk's reads done
#pragma unroll
      for (int k = 0; k < 4; ++k) eS[t + 512 * k] = e4[base + t + 512 * k];
      __syncthreads();
#pragma unroll
      for (int j = 0; j < 16; ++j) {
        int li = lane + 64 * (half * 16 + j);
        float4 a = wrow[base + li], b = eS[li];
        s += a.x * b.x + a.y * b.y + a.z * b.z + a.w * b.w;
      }
    }
    {  // tail chunk: f4 [30720, 32400)
      int base = 30720;
      __syncthreads();
#pragma unroll
      for (int k = 0; k < 4; ++k) {
        int idx = base + t + 512 * k;
        if (idx < 32400) eS[t + 512 * k] = e4[idx];
      }
      __syncthreads();
#pragma unroll
      for (int j = 0; j < 16; ++j) {
        int li = lane + 64 * (half * 16 + j);
        int idx = base + li;
        if (idx < 32400) {
          float4 a = wrow[idx], b = eS[li];
          s += a.x * b.x + a.y * b.y + a.z * b.z + a.w * b.w;
        }
      }
    }
    for (int o = 32; o; o >>= 1) s += __shfl_down(s, o);
    if (lane == 0) sred[w] = s;
    __syncthreads();
    if (t < 4)
      p[blockIdx.x * 4 + t] = fmaxf(sred[t] + sred[t + 4] + bp1[blockIdx.x * 4 + t], 0.f);
  } else {
    __bf16 (*Alds)[40] = (__bf16(*)[40])SM;
    __bf16 (*g1S)[264] = (__bf16(*)[264])(SM + 5120);
    int lane = t & 63, wid = t >> 6;
    int wr = wid >> 2, wc = wid & 3;
    int rowBase = (blockIdx.x - 128) * 64;
    int sr = t >> 3, sc = (t & 7) * 4;
    const float* aSrc = mc + (size_t)(rowBase + sr) * 200;
    int q4 = (lane >> 4) * 4;
    f32x4 acc[2][4] = {};
    for (int kt = 0; kt < 7; ++kt) {
      int gk = kt * 32 + sc;
      bf16x4 w4;
      if (gk < 200) {
        float4 v = *(const float4*)(aSrc + gk);
        w4[0] = (__bf16)v.x; w4[1] = (__bf16)v.y;
        w4[2] = (__bf16)v.z; w4[3] = (__bf16)v.w;
      } else {
        w4[0] = w4[1] = w4[2] = w4[3] = (__bf16)0.f;
      }
      *reinterpret_cast<bf16x4*>(&Alds[sr][sc]) = w4;
      __syncthreads();
      int arow = wr * 32 + (lane & 15), ak = (lane >> 4) * 8;
      bf16x8 a0 = *reinterpret_cast<const bf16x8*>(&Alds[arow][ak]);
      bf16x8 a1 = *reinterpret_cast<const bf16x8*>(&Alds[arow + 16][ak]);
#pragma unroll
      for (int n = 0; n < 4; ++n) {
        bf16x8 bv = ldB(Wg1p, kt, 16, wc * 4 + n, lane);
        acc[0][n] = mfma_bf16(a0, bv, acc[0][n]);
        acc[1][n] = mfma_bf16(a1, bv, acc[1][n]);
      }
      __syncthreads();
    }
#pragma unroll
    for (int m = 0; m < 2; ++m)
#pragma unroll
      for (int n = 0; n < 4; ++n) {
        int col = wc * 64 + n * 16 + (lane & 15);
        float bb = bg1[col];
#pragma unroll
        for (int j = 0; j < 4; ++j) {
          int rl = wr * 32 + m * 16 + q4 + j;
          g1S[rl][col] = (__bf16)fmaxf(acc[m][n][j] + bb, 0.f);
        }
      }
    __syncthreads();
    f32x4 acc2[2][2] = {};
#pragma unroll
    for (int ks = 0; ks < 8; ++ks) {
      int arow = wr * 32 + (lane & 15), ak = ks * 32 + (lane >> 4) * 8;
      bf16x8 a0 = *reinterpret_cast<const bf16x8*>(&g1S[arow][ak]);
      bf16x8 a1 = *reinterpret_cast<const bf16x8*>(&g1S[arow + 16][ak]);
#pragma unroll
      for (int n = 0; n < 2; ++n) {
        bf16x8 bv = ldB(Wg2p, ks, 8, wc * 2 + n, lane);
        acc2[0][n] = mfma_bf16(a0, bv, acc2[0][n]);
        acc2[1][n] = mfma_bf16(a1, bv, acc2[1][n]);
      }
    }
#pragma unroll
    for (int m = 0; m < 2; ++m)
#pragma unroll
      for (int n = 0; n < 2; ++n) {
        int col = wc * 32 + n * 16 + (lane & 15);
        float bb = bg2[col];
#pragma unroll
        for (int j = 0; j < 4; ++j) {
          int row = rowBase + wr * 32 + m * 16 + q4 + j;
          o_zgeo[(size_t)row * 128 + col] = acc2[m][n][j] + bb;
        }
      }
  }
}

// znpi1[j] = bp2[j] + sum_k p[k]*Wp2[j*512+k]; 128 blocks x 64 threads (proven)
__global__ void gemv_z(const float* __restrict__ p, const float* __restrict__ Wp2,
                       const float* __restrict__ bp2, float* __restrict__ znpi1) {
  int j = blockIdx.x;
  int t = threadIdx.x;
  const float4* w = (const float4*)(Wp2 + (size_t)j * 512);
  const float4* pp = (const float4*)p;
  float4 a0 = w[t], b0 = pp[t];
  float4 a1 = w[t + 64], b1 = pp[t + 64];
  float s = a0.x * b0.x + a0.y * b0.y + a0.z * b0.z + a0.w * b0.w +
            a1.x * b1.x + a1.y * b1.y + a1.z * b1.z + a1.w * b1.w;
  for (int o = 32; o; o >>= 1) s += __shfl_down(s, o);
  if (t == 0) znpi1[j] = s + bp2[j];
}

// ---------------------------------------------------------------------------
// Tail: zsum = zgeo + znpi1; zn = normalize(zsum); r1 = relu(zn@Wr1^T+br1);
// recon = r1@Wr2^T+br2. One block = 64 rows, 8 waves. zn, r1 live in LDS.
// ---------------------------------------------------------------------------
__global__ __launch_bounds__(512) void mega_tail(
    const float* __restrict__ zgeo, const float* __restrict__ znpi1,
    const __bf16* __restrict__ Wr1p, const float* __restrict__ br1,
    const __bf16* __restrict__ Wr2p, const float* __restrict__ br2,
    float* __restrict__ o_znpi, float* __restrict__ o_zn,
    float* __restrict__ o_rec) {
  __shared__ __bf16 r1S[64][264];
  __shared__ __bf16 znS[64][136];
  __shared__ float znpiS[128];
  int tid = threadIdx.x;
  int lane = tid & 63, wid = tid >> 6;
  int wr = wid >> 2, wc = wid & 3;
  int rowBase = blockIdx.x * 64;
  int q4 = (lane >> 4) * 4;
  if (tid < 128) znpiS[tid] = znpi1[tid];
  __syncthreads();
  {
    int rg = tid >> 5;
    int c4 = (tid & 31) * 4;
    float4 zp = make_float4(znpiS[c4], znpiS[c4 + 1], znpiS[c4 + 2], znpiS[c4 + 3]);
#pragma unroll
    for (int ri = 0; ri < 4; ++ri) {
      int rl = rg + ri * 16;
      int row = rowBase + rl;
      float4 zg = *(const float4*)(zgeo + (size_t)row * 128 + c4);
      float4 zs = make_float4(zg.x + zp.x, zg.y + zp.y, zg.z + zp.z, zg.w + zp.w);
      *(float4*)(o_znpi + (size_t)row * 128 + c4) = zp;
      float ss = zs.x * zs.x + zs.y * zs.y + zs.z * zs.z + zs.w * zs.w;
      ss += __shfl_xor(ss, 1);
      ss += __shfl_xor(ss, 2);
      ss += __shfl_xor(ss, 4);
      ss += __shfl_xor(ss, 8);
      ss += __shfl_xor(ss, 16);
      float rn = 1.f / fmaxf(sqrtf(ss), 1e-12f);
      float4 zn = make_float4(zs.x * rn, zs.y * rn, zs.z * rn, zs.w * rn);
      *(float4*)(o_zn + (size_t)row * 128 + c4) = zn;
      bf16x4 znb;
      znb[0] = (__bf16)zn.x; znb[1] = (__bf16)zn.y;
      znb[2] = (__bf16)zn.z; znb[3] = (__bf16)zn.w;
      *reinterpret_cast<bf16x4*>(&znS[rl][c4]) = znb;
    }
  }
  __syncthreads();
  {
    f32x4 acc[2][4] = {};
#pragma unroll
    for (int ks = 0; ks < 4; ++ks) {
      int arow = wr * 32 + (lane & 15), ak = ks * 32 + (lane >> 4) * 8;
      bf16x8 a0 = *reinterpret_cast<const bf16x8*>(&znS[arow][ak]);
      bf16x8 a1 = *reinterpret_cast<const bf16x8*>(&znS[arow + 16][ak]);
#pragma unroll
      for (int n = 0; n < 4; ++n) {
        bf16x8 bv = ldB(Wr1p, ks, 16, wc * 4 + n, lane);
        acc[0][n] = mfma_bf16(a0, bv, acc[0][n]);
        acc[1][n] = mfma_bf16(a1, bv, acc[1][n]);
      }
    }
#pragma unroll
    for (int m = 0; m < 2; ++m)
#pragma unroll
      for (int n = 0; n < 4; ++n) {
        int col = wc * 64 + n * 16 + (lane & 15);
        float bb = br1[col];
#pragma unroll
        for (int j = 0; j < 4; ++j) {
          int rl = wr * 32 + m * 16 + q4 + j;
          r1S[rl][col] = (__bf16)fmaxf(acc[m][n][j] + bb, 0.f);
        }
      }
  }
  __syncthreads();
  {
    f32x4 acc[2][6] = {};
#pragma unroll
    for (int ks = 0; ks < 8; ++ks) {
      int arow = wr * 32 + (lane & 15), ak = ks * 32 + (lane >> 4) * 8;
      bf16x8 a0 = *reinterpret_cast<const bf16x8*>(&r1S[arow][ak]);
      bf16x8 a1 = *reinterpret_cast<const bf16x8*>(&r1S[arow + 16][ak]);
#pragma unroll
      for (int n = 0; n < 6; ++n) {
        bf16x8 bv = ldB(Wr2p, ks, 24, wc * 6 + n, lane);
        acc[0][n] = mfma_bf16(a0, bv, acc[0][n]);
        acc[1][n] = mfma_bf16(a1, bv, acc[1][n]);
      }
    }
#pragma unroll
    for (int m = 0; m < 2; ++m)
#pragma unroll
      for (int n = 0; n < 6; ++n) {
        int col = wc * 96 + n * 16 + (lane & 15);
        if (col < 360) {
          float bb = br2[col];
#pragma unroll
          for (int j = 0; j < 4; ++j) {
            int rl = wr * 32 + m * 16 + q4 + j;
            o_rec[(size_t)(rowBase + rl) * 360 + col] = acc[m][n][j] + bb;
          }
        }
      }
  }
}

// ---------------------------------------------------------------------------
extern "C" void kernel_launch(void* const* d_in, const int* in_sizes, int n_in,
                              void* d_out, int out_size, void* d_ws,
                              size_t ws_size, hipStream_t stream) {
  (void)in_sizes; (void)n_in; (void)out_size; (void)ws_size;
  const float* x   = (const float*)d_in[0];
  const float* mc  = (const float*)d_in[2];
  const float* W1  = (const float*)d_in[3];  const float* b1  = (const float*)d_in[4];
  const float* W2  = (const float*)d_in[5];  const float* b2  = (const float*)d_in[6];
  const float* W3  = (const float*)d_in[7];
  const float* Wp1 = (const float*)d_in[9];  const float* bp1 = (const float*)d_in[10];
  const float* Wp2 = (const float*)d_in[11]; const float* bp2 = (const float*)d_in[12];
  const float* Wg1 = (const float*)d_in[13]; const float* bg1 = (const float*)d_in[14];
  const float* Wg2 = (const float*)d_in[15]; const float* bg2 = (const float*)d_in[16];
  const float* Wr1 = (const float*)d_in[17]; const float* br1 = (const float*)d_in[18];
  const float* Wr2 = (const float*)d_in[19]; const float* br2 = (const float*)d_in[20];

  float* out = (float*)d_out;
  float* o_znpi = out;                  // (B,128)
  float* o_zgeo = out + 2097152;        // (B,128)
  float* o_zn   = out + 4194304;        // (B,128)
  float* o_ec   = out + 6291456;        // (360,360)
  float* o_rec  = out + 6421056;        // (B,360)

  char* ws = (char*)d_ws;
  __bf16* m1T    = (__bf16*)(ws + 0);            // (256,16384)
  __bf16* m2T    = (__bf16*)(ws + 8388608);      // (256,16384)
  float*  G      = (float*)(ws + 16777216);      // 256x256
  float*  Tpart  = (float*)(ws + 17039360);      // 4 x 256 x 384
  float*  ecpart = (float*)(ws + 18612224);      // 4 x 360 x 360
  float*  p512   = (float*)(ws + 20686848);      // 512
  float*  znpi1  = (float*)(ws + 20688896);      // 128
  __bf16* W1p    = (__bf16*)(ws + 20689920);
  __bf16* W2p    = W1p  + (size_t)544 * 512;
  __bf16* Wg1p   = W2p  + (size_t)128 * 512;
  __bf16* Wg2p   = Wg1p + (size_t)112 * 512;
  __bf16* Wr1p   = Wg2p + (size_t)64 * 512;
  __bf16* Wr2p   = Wr1p + (size_t)64 * 512;
  int*    cnt    = (int*)(ws + 22020096);        // [0]=small_split bar

  pack_all<<<1136, 64, 0, stream>>>(W1, W2, Wg1, Wg2, Wr1, Wr2,
                                    W1p, W2p, Wg1p, Wg2p, Wr1p, Wr2p, G, cnt);
  h1h2_fused<<<512, 512, 0, stream>>>(x, W1p, b1, W2p, b2, m1T, m2T);
  gemm_masks<<<dim3(4, 4, 16), 256, 0, stream>>>(m2T, m1T, G);
  small_split<<<144, 256, 0, stream>>>(W2, G, W1, W3, Tpart, ecpart, o_ec,
                                       cnt);
  p_and_g1<<<384, 512, 0, stream>>>(Wp1, o_ec, bp1, p512, mc, Wg1p, bg1,
                                    Wg2p, bg2, o_zgeo);
  gemv_z<<<128, 64, 0, stream>>>(p512, Wp2, bp2, znpi1);
  mega_tail<<<256, 512, 0, stream>>>(o_zgeo, znpi1, Wr1p, br1, Wr2p, br2,
                                     o_znpi, o_zn, o_rec);
}

// Round 12
// 221.523 us; speedup vs baseline: 1.4066x; 1.1041x over previous
//
#include <hip/hip_runtime.h>

typedef __bf16 bf16x8 __attribute__((ext_vector_type(8)));
typedef __bf16 bf16x4 __attribute__((ext_vector_type(4)));
typedef float  f32x4  __attribute__((ext_vector_type(4)));

__device__ __forceinline__ f32x4 mfma_bf16(bf16x8 a, bf16x8 b, f32x4 c) {
  return __builtin_amdgcn_mfma_f32_16x16x32_bf16(a, b, c, 0, 0, 0);
}
// Packed B-fragment load: Bp[((kt*NT+nt)*64+lane)*8 .. +7]
__device__ __forceinline__ bf16x8 ldB(const __bf16* Bp, int kt, int NT, int nt,
                                      int lane) {
  return *reinterpret_cast<const bf16x8*>(Bp + (((size_t)kt * NT + nt) * 64 + lane) * 8);
}

// Grid barrier -- ONLY small grids (<=~150 blocks) after uniform light phases.
// R4/R9/R10 lessons: keep device-scope sync OUT of streaming kernels.
__device__ __forceinline__ void gridbar(int* cnt, int target) {
  __syncthreads();
  if (threadIdx.x == 0) {
    __threadfence();
    __hip_atomic_fetch_add(cnt, 1, __ATOMIC_RELEASE, __HIP_MEMORY_SCOPE_AGENT);
    while (__hip_atomic_load(cnt, __ATOMIC_RELAXED, __HIP_MEMORY_SCOPE_AGENT) < target)
      __builtin_amdgcn_s_sleep(4);
    __threadfence();
  }
  __syncthreads();
}

// ---------------------------------------------------------------------------
// All weight packs in ONE kernel + zero G + zero counters.
// ---------------------------------------------------------------------------
__global__ void pack_all(const float* __restrict__ W1, const float* __restrict__ W2,
                         const float* __restrict__ Wg1, const float* __restrict__ Wg2,
                         const float* __restrict__ Wr1, const float* __restrict__ Wr2,
                         __bf16* __restrict__ W1p, __bf16* __restrict__ W2p,
                         __bf16* __restrict__ Wg1p, __bf16* __restrict__ Wg2p,
                         __bf16* __restrict__ Wr1p, __bf16* __restrict__ Wr2p,
                         float* __restrict__ G, int* __restrict__ cnt) {
  int bx = blockIdx.x;
  int lane = threadIdx.x;
  if (bx >= 1104) {  // zero G (256x256 f32): 32 blocks x 64 thr x 8 float4
    if (bx == 1104 && lane < 2) cnt[lane] = 0;  // [0]=small_split bar
    float4* g = (float4*)G;
    int base = (bx - 1104) * 512 + lane;
#pragma unroll
    for (int i = 0; i < 8; ++i) g[base + i * 64] = make_float4(0.f, 0.f, 0.f, 0.f);
    return;
  }
  const float* W; __bf16* out; int N, K, NT, local;
  if (bx < 544)      { W = W1;  out = W1p;  N = 256; K = 1080; NT = 16; local = bx; }
  else if (bx < 672) { W = W2;  out = W2p;  N = 256; K = 256;  NT = 16; local = bx - 544; }
  else if (bx < 784) { W = Wg1; out = Wg1p; N = 256; K = 200;  NT = 16; local = bx - 672; }
  else if (bx < 848) { W = Wg2; out = Wg2p; N = 128; K = 256;  NT = 8;  local = bx - 784; }
  else if (bx < 912) { W = Wr1; out = Wr1p; N = 256; K = 128;  NT = 16; local = bx - 848; }
  else               { W = Wr2; out = Wr2p; N = 360; K = 256;  NT = 24; local = bx - 912; }
  int nt = local % NT, kt = local / NT;
  int n = nt * 16 + (lane & 15);
  int k0 = kt * 32 + (lane >> 4) * 8;
  bf16x8 v;
#pragma unroll
  for (int e = 0; e < 8; ++e) {
    int k = k0 + e;
    float xv = (n < N && k < K) ? W[(size_t)n * K + k] : 0.f;
    v[e] = (__bf16)xv;
  }
  *reinterpret_cast<bf16x8*>(out + ((size_t)local * 64 + lane) * 8) = v;
}

// ---------------------------------------------------------------------------
// Fused surrogate v3 (proven R8): tile 32x256, 8 waves, grid 512 -> 4 waves/SIMD.
// ---------------------------------------------------------------------------
__global__ __launch_bounds__(512) void h1h2_fused(
    const float* __restrict__ x, const __bf16* __restrict__ W1p,
    const float* __restrict__ b1, const __bf16* __restrict__ W2p,
    const float* __restrict__ b2, __bf16* __restrict__ m1T,
    __bf16* __restrict__ m2T) {
  __shared__ __bf16 Alds[32][68];    // 64-wide K-slab, stride 68 (~2-way banks)
  __shared__ __bf16 h1s[32][264];    // relu(h1)
  int tid = threadIdx.x;
  int lane = tid & 63, wid = tid >> 6;
  int wr = wid >> 2, wc = wid & 3;
  int rowBase = blockIdx.x * 32;
  int sr = tid >> 4, sc = (tid & 15) * 4;   // 32 rows x 16 thr x 4 floats
  const float* aSrc = x + (size_t)(rowBase + sr) * 1080;
  f32x4 acc[4] = {};
  float4 c0, c1;
  auto LD = [&](int s, float4& d) {
    int gk = s * 64 + sc;
    d = (gk < 1080) ? *(const float4*)(aSrc + gk) : make_float4(0.f, 0.f, 0.f, 0.f);
  };
  LD(0, c0);
  LD(1, c1);
  for (int s = 0; s < 17; ++s) {
    bf16x4 w4;
    w4[0] = (__bf16)c0.x; w4[1] = (__bf16)c0.y;
    w4[2] = (__bf16)c0.z; w4[3] = (__bf16)c0.w;
    *reinterpret_cast<bf16x4*>(&Alds[sr][sc]) = w4;
    __syncthreads();
    c0 = c1;
    if (s + 2 < 17) LD(s + 2, c1);
    int arow = wr * 16 + (lane & 15);
#pragma unroll
    for (int ks = 0; ks < 2; ++ks) {
      int ak = ks * 32 + (lane >> 4) * 8;
      bf16x8 a0 = *reinterpret_cast<const bf16x8*>(&Alds[arow][ak]);
      int kt = s * 2 + ks;
#pragma unroll
      for (int n = 0; n < 4; ++n) {
        bf16x8 bv = ldB(W1p, kt, 16, wc * 4 + n, lane);
        acc[n] = mfma_bf16(a0, bv, acc[n]);
      }
    }
    __syncthreads();
  }
  int q4 = (lane >> 4) * 4;
#pragma unroll
  for (int n = 0; n < 4; ++n) {
    int col = wc * 64 + n * 16 + (lane & 15);
    float bb = b1[col];
#pragma unroll
    for (int j = 0; j < 4; ++j) {
      int rl = wr * 16 + q4 + j;
      float h = acc[n][j] + bb;
      m1T[(size_t)col * 16384 + rowBase + rl] = (__bf16)(h > 0.f ? 1.f : 0.f);
      h1s[rl][col] = (__bf16)fmaxf(h, 0.f);
    }
  }
  __syncthreads();
  // ---- h2 phase: K=256 from LDS ----
  f32x4 acc2[4] = {};
#pragma unroll
  for (int ks = 0; ks < 8; ++ks) {
    int arow = wr * 16 + (lane & 15), ak = ks * 32 + (lane >> 4) * 8;
    bf16x8 a0 = *reinterpret_cast<const bf16x8*>(&h1s[arow][ak]);
#pragma unroll
    for (int n = 0; n < 4; ++n) {
      bf16x8 bv = ldB(W2p, ks, 16, wc * 4 + n, lane);
      acc2[n] = mfma_bf16(a0, bv, acc2[n]);
    }
  }
#pragma unroll
  for (int n = 0; n < 4; ++n) {
    int col = wc * 64 + n * 16 + (lane & 15);
    float bb = b2[col];
#pragma unroll
    for (int j = 0; j < 4; ++j) {
      int rl = wr * 16 + q4 + j;
      float h = acc2[n][j] + bb;
      m2T[(size_t)col * 16384 + rowBase + rl] = (__bf16)(h > 0.f ? 1.f : 0.f);
    }
  }
}

// ---------------------------------------------------------------------------
// Streaming masks GEMM: G += (1/B) m2^T @ m1 chunks. Exact dyadic atomics.
// ---------------------------------------------------------------------------
__global__ __launch_bounds__(256) void gemm_masks(
    const __bf16* __restrict__ m2T, const __bf16* __restrict__ m1T,
    float* __restrict__ G) {
  int tid = threadIdx.x;
  int lane = tid & 63, wid = tid >> 6;
  int wr = wid >> 1, wc = wid & 1;
  int ibase = blockIdx.x * 64, jbase = blockIdx.y * 64;
  size_t b0 = (size_t)blockIdx.z * 1024 + (lane >> 4) * 8;
  const __bf16* pa0 = m2T + (size_t)(ibase + wr * 32 + (lane & 15)) * 16384 + b0;
  const __bf16* pa1 = pa0 + (size_t)16 * 16384;
  const __bf16* pb0 = m1T + (size_t)(jbase + wc * 32 + (lane & 15)) * 16384 + b0;
  const __bf16* pb1 = pb0 + (size_t)16 * 16384;
  f32x4 acc[2][2] = {};
#pragma unroll 4
  for (int c = 0; c < 32; ++c) {
    bf16x8 a0 = *reinterpret_cast<const bf16x8*>(pa0 + c * 32);
    bf16x8 a1 = *reinterpret_cast<const bf16x8*>(pa1 + c * 32);
    bf16x8 bv0 = *reinterpret_cast<const bf16x8*>(pb0 + c * 32);
    bf16x8 bv1 = *reinterpret_cast<const bf16x8*>(pb1 + c * 32);
    acc[0][0] = mfma_bf16(a0, bv0, acc[0][0]);
    acc[0][1] = mfma_bf16(a0, bv1, acc[0][1]);
    acc[1][0] = mfma_bf16(a1, bv0, acc[1][0]);
    acc[1][1] = mfma_bf16(a1, bv1, acc[1][1]);
  }
  int q4 = (lane >> 4) * 4;
#pragma unroll
  for (int m = 0; m < 2; ++m)
#pragma unroll
    for (int n = 0; n < 2; ++n)
#pragma unroll
      for (int j = 0; j < 4; ++j) {
        int gi = ibase + wr * 32 + m * 16 + q4 + j;
        int gj = jbase + wc * 32 + n * 16 + (lane & 15);
        atomicAdd(&G[(size_t)gi * 256 + gj], acc[m][n][j] * (1.f / 16384.f));
      }
}

// ---------------------------------------------------------------------------
// 64x64-tile f32 GEMM body over K range [kBeg,kEnd).
// ---------------------------------------------------------------------------
__device__ void small_body2(float (*As)[17], float (*Bs)[65], int t,
                            const float* __restrict__ A, const float* __restrict__ A2,
                            int lda, const float* __restrict__ Bm, int ldb,
                            bool sum4, size_t bStride, float* __restrict__ C,
                            int ldc, int M, int N, int kBeg, int kEnd,
                            int m0, int n0) {
  int tx = t & 15, ty = t >> 4;
  float acc[4][4] = {};
  for (int k0 = kBeg; k0 < kEnd; k0 += 16) {
#pragma unroll
    for (int i = 0; i < 4; ++i) {
      int idx = t * 4 + i;
      int r = idx >> 4, kk = idx & 15;
      int gm = m0 + r, gk = k0 + kk;
      float v = (gm < M) ? A[(size_t)gm * lda + gk] : 0.f;
      if (A2 && gm < M) v *= A2[(size_t)gm * lda + gk];
      As[r][kk] = v;
      int kk2 = idx >> 6, cc = idx & 63;
      int gk2 = k0 + kk2, gn = n0 + cc;
      float bv = 0.f;
      if (gn < N) {
        const float* bp = Bm + (size_t)gk2 * ldb + gn;
        bv = bp[0];
        if (sum4) bv = bv + bp[bStride] + bp[2 * bStride] + bp[3 * bStride];
      }
      Bs[kk2][cc] = bv;
    }
    __syncthreads();
#pragma unroll
    for (int kk = 0; kk < 16; ++kk)
#pragma unroll
      for (int i = 0; i < 4; ++i)
#pragma unroll
        for (int j = 0; j < 4; ++j)
          acc[i][j] += As[ty * 4 + i][kk] * Bs[kk][tx * 4 + j];
    __syncthreads();
  }
#pragma unroll
  for (int i = 0; i < 4; ++i)
#pragma unroll
    for (int j = 0; j < 4; ++j) {
      int gm = m0 + ty * 4 + i, gn = n0 + tx * 4 + j;
      if (gm < M && gn < N) C[(size_t)gm * ldc + gn] = acc[i][j];
    }
}

// ---------------------------------------------------------------------------
// ec chain, split-K, ONE kernel (144 blocks, uniform light phases -- proven R8).
// ---------------------------------------------------------------------------
__global__ __launch_bounds__(256) void small_split(
    const float* __restrict__ W2, const float* __restrict__ G,
    const float* __restrict__ W1, const float* __restrict__ W3,
    float* __restrict__ Tpart, float* __restrict__ ecpart,
    float* __restrict__ o_ec, int* __restrict__ cnt) {
  __shared__ float As[64][17];
  __shared__ float Bs[16][65];
  int t = threadIdx.x, bid = blockIdx.x;
  if (bid < 96) {
    int tile = bid >> 2, kc = bid & 3;
    small_body2(As, Bs, t, W2, G, 256, W1 + 720, 1080, false, 0,
                Tpart + (size_t)kc * 98304, 384, 256, 360,
                kc * 64, kc * 64 + 64, (tile / 6) * 64, (tile % 6) * 64);
  }
  gridbar(cnt, 144);
  {
    int tile = bid >> 2, kc = bid & 3;  // 144 = 36 tiles x 4 kc
    small_body2(As, Bs, t, W3, nullptr, 256, Tpart, 384, true, 98304,
                ecpart + (size_t)kc * 129600, 360, 360, 360,
                kc * 64, kc * 64 + 64, (tile / 6) * 64, (tile % 6) * 64);
  }
  gridbar(cnt, 288);
  {
    int base = bid * 900;  // 144 * 900 = 129600
    for (int i = t; i < 900; i += 256) {
      int idx = base + i;
      o_ec[idx] = ecpart[idx] + ecpart[129600 + idx] + ecpart[259200 + idx] +
                  ecpart[388800 + idx];
    }
  }
}

// ---------------------------------------------------------------------------
// p_and_g1 v3 -- R11 lesson: 128 streaming blocks cap Wp1 at ~3 TB/s (per-CU
// stream limit ~24 GB/s). Now 256 gemv blocks x 2 rows (4 waves/row, K split
// in quarters), ec still LDS-chunked (traffic 133MB, L2-served). 512 total
// blocks = 2/CU. No device-scope sync.
// blocks 0..255: gemv arm. blocks 256..511: g1 arm (proven R8 code).
// ---------------------------------------------------------------------------
__global__ __launch_bounds__(512) void p_and_g1(
    const float* __restrict__ Wp1, const float* __restrict__ ec,
    const float* __restrict__ bp1, float* __restrict__ p,
    const float* __restrict__ mc, const __bf16* __restrict__ Wg1p,
    const float* __restrict__ bg1, const __bf16* __restrict__ Wg2p,
    const float* __restrict__ bg2, float* __restrict__ o_zgeo) {
  __shared__ __align__(16) char SM[39424];
  int t = threadIdx.x;
  if (blockIdx.x < 256) {
    float4* eS = (float4*)SM;              // 2048 float4 = 32 KB
    float* sred = (float*)(SM + 32768);    // 8 floats
    int lane = t & 63, w = t >> 6;         // 8 waves
    int r = w & 1;                         // row within block (0,1)
    int q = w >> 1;                        // K-quarter (0..3)
    int row = blockIdx.x * 2 + r;
    const float4* wrow = (const float4*)(Wp1 + (size_t)row * 129600);
    const float4* e4 = (const float4*)ec;
    float s = 0.f;
    for (int c = 0; c < 15; ++c) {         // full chunks: f4 [c*2048, +2048)
      int base = c * 2048;
      __syncthreads();                     // previous chunk's reads done
#pragma unroll
      for (int k = 0; k < 4; ++k) eS[t + 512 * k] = e4[base + t + 512 * k];
      __syncthreads();
#pragma unroll
      for (int j = 0; j < 8; ++j) {
        int li = q * 512 + j * 64 + lane;
        float4 a = wrow[base + li], b = eS[li];
        s += a.x * b.x + a.y * b.y + a.z * b.z + a.w * b.w;
      }
    }
    {  // tail chunk: f4 [30720, 32400)
      int base = 30720;
      __syncthreads();
#pragma unroll
      for (int k = 0; k < 4; ++k) {
        int idx = base + t + 512 * k;
        if (idx < 32400) eS[t + 512 * k] = e4[idx];
      }
      __syncthreads();
#pragma unroll
      for (int j = 0; j < 8; ++j) {
        int li = q * 512 + j * 64 + lane;
        int idx = base + li;
        if (idx < 32400) {
          float4 a = wrow[idx], b = eS[li];
          s += a.x * b.x + a.y * b.y + a.z * b.z + a.w * b.w;
        }
      }
    }
    for (int o = 32; o; o >>= 1) s += __shfl_down(s, o);
    if (lane == 0) sred[w] = s;            // sred[q*2 + r]
    __syncthreads();
    if (t < 2) {
      int row2 = blockIdx.x * 2 + t;
      p[row2] = fmaxf(sred[t] + sred[t + 2] + sred[t + 4] + sred[t + 6] +
                          bp1[row2], 0.f);
    }
  } else {
    __bf16 (*Alds)[40] = (__bf16(*)[40])SM;
    __bf16 (*g1S)[264] = (__bf16(*)[264])(SM + 5120);
    int lane = t & 63, wid = t >> 6;
    int wr = wid >> 2, wc = wid & 3;
    int rowBase = (blockIdx.x - 256) * 64;
    int sr = t >> 3, sc = (t & 7) * 4;
    const float* aSrc = mc + (size_t)(rowBase + sr) * 200;
    int q4 = (lane >> 4) * 4;
    f32x4 acc[2][4] = {};
    for (int kt = 0; kt < 7; ++kt) {
      int gk = kt * 32 + sc;
      bf16x4 w4;
      if (gk < 200) {
        float4 v = *(const float4*)(aSrc + gk);
        w4[0] = (__bf16)v.x; w4[1] = (__bf16)v.y;
        w4[2] = (__bf16)v.z; w4[3] = (__bf16)v.w;
      } else {
        w4[0] = w4[1] = w4[2] = w4[3] = (__bf16)0.f;
      }
      *reinterpret_cast<bf16x4*>(&Alds[sr][sc]) = w4;
      __syncthreads();
      int arow = wr * 32 + (lane & 15), ak = (lane >> 4) * 8;
      bf16x8 a0 = *reinterpret_cast<const bf16x8*>(&Alds[arow][ak]);
      bf16x8 a1 = *reinterpret_cast<const bf16x8*>(&Alds[arow + 16][ak]);
#pragma unroll
      for (int n = 0; n < 4; ++n) {
        bf16x8 bv = ldB(Wg1p, kt, 16, wc * 4 + n, lane);
        acc[0][n] = mfma_bf16(a0, bv, acc[0][n]);
        acc[1][n] = mfma_bf16(a1, bv, acc[1][n]);
      }
      __syncthreads();
    }
#pragma unroll
    for (int m = 0; m < 2; ++m)
#pragma unroll
      for (int n = 0; n < 4; ++n) {
        int col = wc * 64 + n * 16 + (lane & 15);
        float bb = bg1[col];
#pragma unroll
        for (int j = 0; j < 4; ++j) {
          int rl = wr * 32 + m * 16 + q4 + j;
          g1S[rl][col] = (__bf16)fmaxf(acc[m][n][j] + bb, 0.f);
        }
      }
    __syncthreads();
    f32x4 acc2[2][2] = {};
#pragma unroll
    for (int ks = 0; ks < 8; ++ks) {
      int arow = wr * 32 + (lane & 15), ak = ks * 32 + (lane >> 4) * 8;
      bf16x8 a0 = *reinterpret_cast<const bf16x8*>(&g1S[arow][ak]);
      bf16x8 a1 = *reinterpret_cast<const bf16x8*>(&g1S[arow + 16][ak]);
#pragma unroll
      for (int n = 0; n < 2; ++n) {
        bf16x8 bv = ldB(Wg2p, ks, 8, wc * 2 + n, lane);
        acc2[0][n] = mfma_bf16(a0, bv, acc2[0][n]);
        acc2[1][n] = mfma_bf16(a1, bv, acc2[1][n]);
      }
    }
#pragma unroll
    for (int m = 0; m < 2; ++m)
#pragma unroll
      for (int n = 0; n < 2; ++n) {
        int col = wc * 32 + n * 16 + (lane & 15);
        float bb = bg2[col];
#pragma unroll
        for (int j = 0; j < 4; ++j) {
          int row = rowBase + wr * 32 + m * 16 + q4 + j;
          o_zgeo[(size_t)row * 128 + col] = acc2[m][n][j] + bb;
        }
      }
  }
}

// znpi1[j] = bp2[j] + sum_k p[k]*Wp2[j*512+k]; 128 blocks x 64 threads (proven)
__global__ void gemv_z(const float* __restrict__ p, const float* __restrict__ Wp2,
                       const float* __restrict__ bp2, float* __restrict__ znpi1) {
  int j = blockIdx.x;
  int t = threadIdx.x;
  const float4* w = (const float4*)(Wp2 + (size_t)j * 512);
  const float4* pp = (const float4*)p;
  float4 a0 = w[t], b0 = pp[t];
  float4 a1 = w[t + 64], b1 = pp[t + 64];
  float s = a0.x * b0.x + a0.y * b0.y + a0.z * b0.z + a0.w * b0.w +
            a1.x * b1.x + a1.y * b1.y + a1.z * b1.z + a1.w * b1.w;
  for (int o = 32; o; o >>= 1) s += __shfl_down(s, o);
  if (t == 0) znpi1[j] = s + bp2[j];
}

// ---------------------------------------------------------------------------
// Tail: zsum = zgeo + znpi1; zn = normalize(zsum); r1 = relu(zn@Wr1^T+br1);
// recon = r1@Wr2^T+br2. One block = 64 rows, 8 waves. zn, r1 live in LDS.
// ---------------------------------------------------------------------------
__global__ __launch_bounds__(512) void mega_tail(
    const float* __restrict__ zgeo, const float* __restrict__ znpi1,
    const __bf16* __restrict__ Wr1p, const float* __restrict__ br1,
    const __bf16* __restrict__ Wr2p, const float* __restrict__ br2,
    float* __restrict__ o_znpi, float* __restrict__ o_zn,
    float* __restrict__ o_rec) {
  __shared__ __bf16 r1S[64][264];
  __shared__ __bf16 znS[64][136];
  __shared__ float znpiS[128];
  int tid = threadIdx.x;
  int lane = tid & 63, wid = tid >> 6;
  int wr = wid >> 2, wc = wid & 3;
  int rowBase = blockIdx.x * 64;
  int q4 = (lane >> 4) * 4;
  if (tid < 128) znpiS[tid] = znpi1[tid];
  __syncthreads();
  {
    int rg = tid >> 5;
    int c4 = (tid & 31) * 4;
    float4 zp = make_float4(znpiS[c4], znpiS[c4 + 1], znpiS[c4 + 2], znpiS[c4 + 3]);
#pragma unroll
    for (int ri = 0; ri < 4; ++ri) {
      int rl = rg + ri * 16;
      int row = rowBase + rl;
      float4 zg = *(const float4*)(zgeo + (size_t)row * 128 + c4);
      float4 zs = make_float4(zg.x + zp.x, zg.y + zp.y, zg.z + zp.z, zg.w + zp.w);
      *(float4*)(o_znpi + (size_t)row * 128 + c4) = zp;
      float ss = zs.x * zs.x + zs.y * zs.y + zs.z * zs.z + zs.w * zs.w;
      ss += __shfl_xor(ss, 1);
      ss += __shfl_xor(ss, 2);
      ss += __shfl_xor(ss, 4);
      ss += __shfl_xor(ss, 8);
      ss += __shfl_xor(ss, 16);
      float rn = 1.f / fmaxf(sqrtf(ss), 1e-12f);
      float4 zn = make_float4(zs.x * rn, zs.y * rn, zs.z * rn, zs.w * rn);
      *(float4*)(o_zn + (size_t)row * 128 + c4) = zn;
      bf16x4 znb;
      znb[0] = (__bf16)zn.x; znb[1] = (__bf16)zn.y;
      znb[2] = (__bf16)zn.z; znb[3] = (__bf16)zn.w;
      *reinterpret_cast<bf16x4*>(&znS[rl][c4]) = znb;
    }
  }
  __syncthreads();
  {
    f32x4 acc[2][4] = {};
#pragma unroll
    for (int ks = 0; ks < 4; ++ks) {
      int arow = wr * 32 + (lane & 15), ak = ks * 32 + (lane >> 4) * 8;
      bf16x8 a0 = *reinterpret_cast<const bf16x8*>(&znS[arow][ak]);
      bf16x8 a1 = *reinterpret_cast<const bf16x8*>(&znS[arow + 16][ak]);
#pragma unroll
      for (int n = 0; n < 4; ++n) {
        bf16x8 bv = ldB(Wr1p, ks, 16, wc * 4 + n, lane);
        acc[0][n] = mfma_bf16(a0, bv, acc[0][n]);
        acc[1][n] = mfma_bf16(a1, bv, acc[1][n]);
      }
    }
#pragma unroll
    for (int m = 0; m < 2; ++m)
#pragma unroll
      for (int n = 0; n < 4; ++n) {
        int col = wc * 64 + n * 16 + (lane & 15);
        float bb = br1[col];
#pragma unroll
        for (int j = 0; j < 4; ++j) {
          int rl = wr * 32 + m * 16 + q4 + j;
          r1S[rl][col] = (__bf16)fmaxf(acc[m][n][j] + bb, 0.f);
        }
      }
  }
  __syncthreads();
  {
    f32x4 acc[2][6] = {};
#pragma unroll
    for (int ks = 0; ks < 8; ++ks) {
      int arow = wr * 32 + (lane & 15), ak = ks * 32 + (lane >> 4) * 8;
      bf16x8 a0 = *reinterpret_cast<const bf16x8*>(&r1S[arow][ak]);
      bf16x8 a1 = *reinterpret_cast<const bf16x8*>(&r1S[arow + 16][ak]);
#pragma unroll
      for (int n = 0; n < 6; ++n) {
        bf16x8 bv = ldB(Wr2p, ks, 24, wc * 6 + n, lane);
        acc[0][n] = mfma_bf16(a0, bv, acc[0][n]);
        acc[1][n] = mfma_bf16(a1, bv, acc[1][n]);
      }
    }
#pragma unroll
    for (int m = 0; m < 2; ++m)
#pragma unroll
      for (int n = 0; n < 6; ++n) {
        int col = wc * 96 + n * 16 + (lane & 15);
        if (col < 360) {
          float bb = br2[col];
#pragma unroll
          for (int j = 0; j < 4; ++j) {
            int rl = wr * 32 + m * 16 + q4 + j;
            o_rec[(size_t)(rowBase + rl) * 360 + col] = acc[m][n][j] + bb;
          }
        }
      }
  }
}

// ---------------------------------------------------------------------------
extern "C" void kernel_launch(void* const* d_in, const int* in_sizes, int n_in,
                              void* d_out, int out_size, void* d_ws,
                              size_t ws_size, hipStream_t stream) {
  (void)in_sizes; (void)n_in; (void)out_size; (void)ws_size;
  const float* x   = (const float*)d_in[0];
  const float* mc  = (const float*)d_in[2];
  const float* W1  = (const float*)d_in[3];  const float* b1  = (const float*)d_in[4];
  const float* W2  = (const float*)d_in[5];  const float* b2  = (const float*)d_in[6];
  const float* W3  = (const float*)d_in[7];
  const float* Wp1 = (const float*)d_in[9];  const float* bp1 = (const float*)d_in[10];
  const float* Wp2 = (const float*)d_in[11]; const float* bp2 = (const float*)d_in[12];
  const float* Wg1 = (const float*)d_in[13]; const float* bg1 = (const float*)d_in[14];
  const float* Wg2 = (const float*)d_in[15]; const float* bg2 = (const float*)d_in[16];
  const float* Wr1 = (const float*)d_in[17]; const float* br1 = (const float*)d_in[18];
  const float* Wr2 = (const float*)d_in[19]; const float* br2 = (const float*)d_in[20];

  float* out = (float*)d_out;
  float* o_znpi = out;                  // (B,128)
  float* o_zgeo = out + 2097152;        // (B,128)
  float* o_zn   = out + 4194304;        // (B,128)
  float* o_ec   = out + 6291456;        // (360,360)
  float* o_rec  = out + 6421056;        // (B,360)

  char* ws = (char*)d_ws;
  __bf16* m1T    = (__bf16*)(ws + 0);            // (256,16384)
  __bf16* m2T    = (__bf16*)(ws + 8388608);      // (256,16384)
  float*  G      = (float*)(ws + 16777216);      // 256x256
  float*  Tpart  = (float*)(ws + 17039360);      // 4 x 256 x 384
  float*  ecpart = (float*)(ws + 18612224);      // 4 x 360 x 360
  float*  p512   = (float*)(ws + 20686848);      // 512
  float*  znpi1  = (float*)(ws + 20688896);      // 128
  __bf16* W1p    = (__bf16*)(ws + 20689920);
  __bf16* W2p    = W1p  + (size_t)544 * 512;
  __bf16* Wg1p   = W2p  + (size_t)128 * 512;
  __bf16* Wg2p   = Wg1p + (size_t)112 * 512;
  __bf16* Wr1p   = Wg2p + (size_t)64 * 512;
  __bf16* Wr2p   = Wr1p + (size_t)64 * 512;
  int*    cnt    = (int*)(ws + 22020096);        // [0]=small_split bar

  pack_all<<<1136, 64, 0, stream>>>(W1, W2, Wg1, Wg2, Wr1, Wr2,
                                    W1p, W2p, Wg1p, Wg2p, Wr1p, Wr2p, G, cnt);
  h1h2_fused<<<512, 512, 0, stream>>>(x, W1p, b1, W2p, b2, m1T, m2T);
  gemm_masks<<<dim3(4, 4, 16), 256, 0, stream>>>(m2T, m1T, G);
  small_split<<<144, 256, 0, stream>>>(W2, G, W1, W3, Tpart, ecpart, o_ec,
                                       cnt);
  p_and_g1<<<512, 512, 0, stream>>>(Wp1, o_ec, bp1, p512, mc, Wg1p, bg1,
                                    Wg2p, bg2, o_zgeo);
  gemv_z<<<128, 64, 0, stream>>>(p512, Wp2, bp2, znpi1);
  mega_tail<<<256, 512, 0, stream>>>(o_zgeo, znpi1, Wr1p, br1, Wr2p, br2,
                                     o_znpi, o_zn, o_rec);
}